// Round 9
// baseline (389.527 us; speedup 1.0000x reference)
//
#include <hip/hip_runtime.h>
#include <math.h>

#define NOBJ 100000
#define SMOOTH 12.0f

typedef __attribute__((ext_vector_type(8))) short bf16x8;
typedef __attribute__((ext_vector_type(4))) float f32x4;
typedef unsigned short u16;
typedef unsigned int u32;
typedef unsigned long long u64;

// bf16 weight table
#define OFF_UWI 0
#define OFF_UWO 4096
#define OFF_BWI 8192
#define OFF_BWO 24576
#define OFF_TWI 40960
#define OFF_TWO 77824
#define OFF_PWI 114688
#define OFF_PWO 131072
#define WTOT    139264
__device__ u16 g_wbf[WTOT];

__device__ __forceinline__ u16 f2b(float x) {
    union { float f; u32 u; } v; v.f = x;
    u32 r = v.u + 0x7FFFu + ((v.u >> 16) & 1);  // RNE
    return (u16)(r >> 16);
}
__device__ __forceinline__ float b2f(u16 b) {
    union { u32 u; float f; } v; v.u = ((u32)b) << 16; return v.f;
}
__device__ __forceinline__ float mish_fast(float x) {
    float e = __expf(fminf(x, 15.f));
    float t = __builtin_fmaf(e, e, 2.f * e);
    return x * t * __builtin_amdgcn_rcpf(t + 2.f);
}
__device__ __forceinline__ double exp12_f64(float m) {
    float t = m * (SMOOTH * 1.4426950408889634f);
    float n = floorf(t);
    float f = exp2f(t - n);
    return ldexp((double)f, (int)n);
}
__device__ __forceinline__ float lse_from_sum(double S) {
    if (S == 0.0) return -3.0701134573253942f;  // log(1e-16)/12
    union { double d; u64 u; } vu; vu.d = S;
    int k = (int)((vu.u >> 52) & 0x7FF) - 1022;
    vu.u = (vu.u & 0x000FFFFFFFFFFFFFULL) | 0x3FE0000000000000ULL;
    float fr = (float)vu.d;
    return ((float)k + __log2f(fr)) * 0.057762265046662105f;  // *ln2/12
}

// weights -> bf16 table, emb -> bf16 table, zero counts/cursor
__global__ void prep_kernel(const float* __restrict__ uwi, const float* __restrict__ uwo,
                            const float* __restrict__ bwi, const float* __restrict__ bwo,
                            const float* __restrict__ twi, const float* __restrict__ two_,
                            const float* __restrict__ pwi, const float* __restrict__ pwo,
                            const float* __restrict__ emb, u16* __restrict__ emb_bf,
                            u32* __restrict__ counts, u32* __restrict__ cursor) {
    int i = blockIdx.x * 256 + threadIdx.x;
    if (i < WTOT) {
        const float* src; int off;
        if      (i < OFF_UWO) { src = uwi; off = OFF_UWI; }
        else if (i < OFF_BWI) { src = uwo; off = OFF_UWO; }
        else if (i < OFF_BWO) { src = bwi; off = OFF_BWI; }
        else if (i < OFF_TWI) { src = bwo; off = OFF_BWO; }
        else if (i < OFF_TWO) { src = twi; off = OFF_TWI; }
        else if (i < OFF_PWI) { src = two_; off = OFF_TWO; }
        else if (i < OFF_PWO) { src = pwi; off = OFF_PWI; }
        else                  { src = pwo; off = OFF_PWO; }
        g_wbf[i] = f2b(src[i - off]);
    }
    if (i < NOBJ * 16) {
        float4 v = ((const float4*)emb)[i];
        ushort4 o;
        o.x = f2b(v.x); o.y = f2b(v.y); o.z = f2b(v.z); o.w = f2b(v.w);
        ((ushort4*)emb_bf)[i] = o;
    }
    if (counts && i < NOBJ) { counts[i] = 0u; cursor[i] = 0u; }
}

__device__ __forceinline__ int lookup_obj(long long m,
                                          const int* __restrict__ iu, int nU,
                                          const int* __restrict__ ib, int nB,
                                          const int* __restrict__ it) {
    if (m < nU) return iu[m];
    m -= nU;
    if (m < nB) return ib[m];
    return it[m - nB];
}

// ---------- CSR build ----------
__global__ void hist_kernel(const int* __restrict__ iu, int nU,
                            const int* __restrict__ ib, int nB,
                            const int* __restrict__ it, int nT,
                            u32* __restrict__ counts) {
    long long t = (long long)blockIdx.x * 256 + threadIdx.x;
    if (t >= (long long)nU + nB + nT) return;
    atomicAdd(&counts[lookup_obj(t, iu, nU, ib, nB, it)], 1u);
}

__global__ void scan1_kernel(const u32* __restrict__ counts, u32* __restrict__ offs,
                             u32* __restrict__ bsum) {
    __shared__ u32 s[256];
    int t = threadIdx.x;
    int g = blockIdx.x * 256 + t;
    u32 v = (g < NOBJ) ? counts[g] : 0u;
    s[t] = v; __syncthreads();
    for (int off = 1; off < 256; off <<= 1) {
        u32 x = (t >= off) ? s[t - off] : 0u; __syncthreads();
        s[t] += x; __syncthreads();
    }
    if (g < NOBJ) offs[g] = s[t] - v;
    if (t == 255) bsum[blockIdx.x] = s[255];
}

__global__ void scan2_kernel(u32* __restrict__ bsum, int nblk) {
    __shared__ u32 s[512];
    int t = threadIdx.x;
    u32 v = (t < nblk) ? bsum[t] : 0u;
    s[t] = v; __syncthreads();
    for (int off = 1; off < 512; off <<= 1) {
        u32 x = (t >= off) ? s[t - off] : 0u; __syncthreads();
        s[t] += x; __syncthreads();
    }
    if (t < nblk) bsum[t] = s[t] - v;
}

__global__ void slot_kernel(const int* __restrict__ iu, int nU,
                            const int* __restrict__ ib, int nB,
                            const int* __restrict__ it, int nT,
                            const u32* __restrict__ offs, const u32* __restrict__ bsum,
                            u32* __restrict__ cursor, u32* __restrict__ slotByRef) {
    long long t = (long long)blockIdx.x * 256 + threadIdx.x;
    if (t >= (long long)nU + nB + nT) return;
    int obj = lookup_obj(t, iu, nU, ib, nB, it);
    u32 pos = atomicAdd(&cursor[obj], 1u);
    slotByRef[t] = offs[obj] + bsum[obj >> 8] + pos;
}

// ---------- fused relation MLP (LDS-staged weights) ----------
// xs: x -> h -> msg in place (strip-local). wlds: 64-k-col weight chunks, shared.
// MODE 2: f64 atomicAdd exp(12*m) | MODE 3: CSR slot-directed f16 msg write
template<int D, int MW, int MODE, int WOFF_I, int WOFF_O>
__global__ __launch_bounds__(64 * MW)
void rel_pass_mfma(const u16* __restrict__ emb_bf,
                   const int* __restrict__ idx, int nRows,
                   const float* __restrict__ bi, const float* __restrict__ bo,
                   double* __restrict__ ssum64,
                   u16* __restrict__ msgs_out, const u32* __restrict__ slotByRef,
                   long long baseRef) {
    constexpr int ARITY = D / 64;
    constexpr int NT = D / 16;
    constexpr int NSC = D / 64;       // 64-k-col stages per layer
    constexpr int M = MW * 16;
    __shared__ u16 xs[M * D];
    __shared__ u16 wlds[D * 64];
    __shared__ int objsm[M * ARITY];
    __shared__ u32 slotm[M * ARITY];

    const int tid = threadIdx.x;
    const int w = tid >> 6, l = tid & 63;
    const int lo = l & 15, hi = l >> 4;
    const int row0 = blockIdx.x * M;

    for (int i = tid; i < M * ARITY; i += 64 * MW) {
        int row = row0 + i / ARITY;
        bool ok = (row < nRows);
        objsm[i] = ok ? idx[(size_t)row * ARITY + i % ARITY] : -1;
        if (MODE == 3)
            slotm[i] = ok ? slotByRef[baseRef + (long long)row0 * ARITY + i] : 0xFFFFFFFFu;
    }
    __syncthreads();

    // bf16 gather: 16B per lane-iteration, XOR-swizzled LDS
    for (int i = tid; i < M * D / 8; i += 64 * MW) {
        int r = i / (D / 8), c8 = i % (D / 8);
        int obj = objsm[r * ARITY + (c8 >> 3)];
        bf16x8 v = {0, 0, 0, 0, 0, 0, 0, 0};
        if (obj >= 0) v = *(const bf16x8*)(emb_bf + (size_t)obj * 64 + (c8 & 7) * 8);
        *(bf16x8*)&xs[(r * D + c8 * 8) ^ ((r & 7) << 3)] = v;
    }

    f32x4 acc[NT];
    const int arow = w * 16 + lo;
    const int asw = (arow & 7) << 3;

    // ---- layer 1: y1 = x @ wi^T + bi ----
#pragma unroll
    for (int n = 0; n < NT; ++n) { float b = bi[n * 16 + lo]; acc[n] = (f32x4){b, b, b, b}; }
#pragma unroll
    for (int sc = 0; sc < NSC; ++sc) {
        __syncthreads();
        for (int i = tid; i < D * 8; i += 64 * MW) {
            int u = i * 8;
            int j = u >> 6;
            bf16x8 v = *(const bf16x8*)&g_wbf[WOFF_I + j * D + sc * 64 + (u & 63)];
            *(bf16x8*)&wlds[u ^ ((j & 7) << 3)] = v;
        }
        __syncthreads();
#pragma unroll
        for (int kkL = 0; kkL < 2; ++kkL) {
            bf16x8 a = *(const bf16x8*)&xs[(arow * D + (sc * 2 + kkL) * 32 + hi * 8) ^ asw];
#pragma unroll
            for (int n = 0; n < NT; ++n) {
                int j = n * 16 + lo;
                bf16x8 b = *(const bf16x8*)&wlds[(j * 64 + kkL * 32 + hi * 8) ^ ((j & 7) << 3)];
                acc[n] = __builtin_amdgcn_mfma_f32_16x16x32_bf16(a, b, acc[n], 0, 0, 0);
            }
        }
    }

    // mish -> own strip; fold residual x + bo into layer-2 acc init
#pragma unroll
    for (int n = 0; n < NT; ++n) {
        float bov = bo[n * 16 + lo];
#pragma unroll
        for (int r = 0; r < 4; ++r) {
            int row = w * 16 + hi * 4 + r;
            int col = n * 16 + lo;
            int sidx = (row * D + col) ^ ((row & 7) << 3);
            float xv = b2f(xs[sidx]);
            xs[sidx] = f2b(mish_fast(acc[n][r]));
            acc[n][r] = bov + xv;
        }
    }

    // ---- layer 2: m = h @ wo^T + (bo + x) ----
#pragma unroll
    for (int sc = 0; sc < NSC; ++sc) {
        __syncthreads();
        for (int i = tid; i < D * 8; i += 64 * MW) {
            int u = i * 8;
            int j = u >> 6;
            bf16x8 v = *(const bf16x8*)&g_wbf[WOFF_O + j * D + sc * 64 + (u & 63)];
            *(bf16x8*)&wlds[u ^ ((j & 7) << 3)] = v;
        }
        __syncthreads();
#pragma unroll
        for (int kkL = 0; kkL < 2; ++kkL) {
            bf16x8 a = *(const bf16x8*)&xs[(arow * D + (sc * 2 + kkL) * 32 + hi * 8) ^ asw];
#pragma unroll
            for (int n = 0; n < NT; ++n) {
                int j = n * 16 + lo;
                bf16x8 b = *(const bf16x8*)&wlds[(j * 64 + kkL * 32 + hi * 8) ^ ((j & 7) << 3)];
                acc[n] = __builtin_amdgcn_mfma_f32_16x16x32_bf16(a, b, acc[n], 0, 0, 0);
            }
        }
    }

    if (MODE == 3) {
#pragma unroll
        for (int n = 0; n < NT; ++n) {
            int col = n * 16 + lo;
#pragma unroll
            for (int r = 0; r < 4; ++r) {
                int row = w * 16 + hi * 4 + r;
                _Float16 hv = (_Float16)acc[n][r];
                xs[(row * D + col) ^ ((row & 7) << 3)] = *(u16*)&hv;
            }
        }
        __syncthreads();
        for (int i = tid; i < M * D / 8; i += 64 * MW) {
            int u = i * 8;
            int row = u / D, off = u - row * D;
            u32 slot = slotm[row * ARITY + (off >> 6)];
            if (slot == 0xFFFFFFFFu) continue;
            *(bf16x8*)(msgs_out + (size_t)slot * 64 + (off & 63)) =
                *(const bf16x8*)&xs[u ^ ((row & 7) << 3)];
        }
    } else {
#pragma unroll
        for (int n = 0; n < NT; ++n) {
            int col = n * 16 + lo;
#pragma unroll
            for (int r = 0; r < 4; ++r) {
                int row = w * 16 + hi * 4 + r;
                int obj = objsm[row * ARITY + (col >> 6)];
                if (obj < 0) continue;
                unsafeAtomicAdd(&ssum64[(size_t)obj * 64 + (col & 63)], exp12_f64(acc[n][r]));
            }
        }
    }
}

// ---------- fused aggregate (8-row vectorized stream) + update MLP ----------
// Zero cross-wave LDS coupling: uin strip-local, colsum per-wave, no __syncthreads.
__global__ __launch_bounds__(256)
void agg_update(const float* __restrict__ emb, const u16* __restrict__ msgs,
                const u32* __restrict__ offs, const u32* __restrict__ bsum,
                const u32* __restrict__ counts,
                const float* __restrict__ bi, const float* __restrict__ bo,
                float* __restrict__ out) {
    __shared__ u16 uin[64 * 128];
    __shared__ double colsum[4][64];
    const int tid = threadIdx.x;
    const int w = tid >> 6, l = tid & 63, lo = l & 15, hi = l >> 4;
    const int rl = l >> 3, c8 = l & 7;
    const int row0 = blockIdx.x * 64;

    // preload CSR meta for this wave's 16 objects into lanes 0..15
    u32 off_l = 0, n_l = 0;
    {
        int o = row0 + w * 16 + lo;
        if (hi == 0 && o < NOBJ) { off_l = offs[o] + bsum[o >> 8]; n_l = counts[o]; }
    }

    for (int rr = 0; rr < 16; ++rr) {
        int row = w * 16 + rr;
        int obj = row0 + row;
        float lse = -3.0701134573253942f, ev = 0.f;
        if (obj < NOBJ) {
            u32 off = __shfl(off_l, rr);
            u32 n = __shfl(n_l, rr);
            // lane (rl,c8): rows off+j+rl, cols c8*8..+7, 16B loads
            double s[8] = {0.0, 0.0, 0.0, 0.0, 0.0, 0.0, 0.0, 0.0};
            for (u32 j = 0; j < n; j += 8) {
                if (j + (u32)rl < n) {
                    bf16x8 v = *(const bf16x8*)(msgs + (size_t)(off + j + rl) * 64 + c8 * 8);
#pragma unroll
                    for (int k = 0; k < 8; ++k) {
                        u16 hb = (u16)v[k];
                        float f = (float)(*(const _Float16*)&hb);
                        s[k] += exp12_f64(f);
                    }
                }
            }
            // reduce-scatter across rl (masks 8,16,32); static element indices
            double t0 = __shfl_xor(s[0], 8), t1 = __shfl_xor(s[1], 8);
            double t2 = __shfl_xor(s[2], 8), t3 = __shfl_xor(s[3], 8);
            double t4 = __shfl_xor(s[4], 8), t5 = __shfl_xor(s[5], 8);
            double t6 = __shfl_xor(s[6], 8), t7 = __shfl_xor(s[7], 8);
            bool bb0 = (rl & 1) != 0;
            double a0 = bb0 ? (s[4] + t4) : (s[0] + t0);
            double a1 = bb0 ? (s[5] + t5) : (s[1] + t1);
            double a2 = bb0 ? (s[6] + t6) : (s[2] + t2);
            double a3 = bb0 ? (s[7] + t7) : (s[3] + t3);
            double u0 = __shfl_xor(a0, 16), u1 = __shfl_xor(a1, 16);
            double u2 = __shfl_xor(a2, 16), u3 = __shfl_xor(a3, 16);
            bool bb1 = (rl & 2) != 0;
            double c0 = bb1 ? (a2 + u2) : (a0 + u0);
            double c1 = bb1 ? (a3 + u3) : (a1 + u1);
            double v0 = __shfl_xor(c0, 32), v1 = __shfl_xor(c1, 32);
            double dfin = ((rl & 4) != 0) ? (c1 + v1) : (c0 + v0);
            // lane holds col = 8*c8 + rev3(rl)
            int col = c8 * 8 + ((rl & 1) << 2) + (rl & 2) + ((rl >> 2) & 1);
            colsum[w][col] = dfin;
            asm volatile("s_waitcnt lgkmcnt(0)" ::: "memory");
            __builtin_amdgcn_sched_barrier(0);
            double S = colsum[w][l];
            lse = lse_from_sum(S);
            ev = emb[(size_t)obj * 64 + l];
        }
        uin[(row * 128 + l) ^ ((row & 7) << 3)] = f2b(lse);
        uin[(row * 128 + 64 + l) ^ ((row & 7) << 3)] = f2b(ev);
    }
    // uin is strip-local per wave: no block barrier needed anywhere below.

    const int arow = w * 16 + lo;
    const int asw = (arow & 7) << 3;
    f32x4 acc[8];
#pragma unroll
    for (int n = 0; n < 8; ++n) { float b = bi[n * 16 + lo]; acc[n] = (f32x4){b, b, b, b}; }
#pragma unroll
    for (int kk = 0; kk < 4; ++kk) {
        bf16x8 a = *(const bf16x8*)&uin[(arow * 128 + kk * 32 + hi * 8) ^ asw];
#pragma unroll
        for (int n = 0; n < 8; ++n) {
            bf16x8 b = *(const bf16x8*)&g_wbf[OFF_PWI + (n * 16 + lo) * 128 + kk * 32 + hi * 8];
            acc[n] = __builtin_amdgcn_mfma_f32_16x16x32_bf16(a, b, acc[n], 0, 0, 0);
        }
    }
    // mish -> own strip in place
#pragma unroll
    for (int n = 0; n < 8; ++n) {
#pragma unroll
        for (int r = 0; r < 4; ++r) {
            int row = w * 16 + hi * 4 + r;
            int col = n * 16 + lo;
            uin[(row * 128 + col) ^ ((row & 7) << 3)] = f2b(mish_fast(acc[n][r]));
        }
    }

    f32x4 acc2[4];
#pragma unroll
    for (int n = 0; n < 4; ++n) { float b = bo[n * 16 + lo]; acc2[n] = (f32x4){b, b, b, b}; }
#pragma unroll
    for (int kk = 0; kk < 4; ++kk) {
        bf16x8 a = *(const bf16x8*)&uin[(arow * 128 + kk * 32 + hi * 8) ^ asw];
#pragma unroll
        for (int n = 0; n < 4; ++n) {
            bf16x8 b = *(const bf16x8*)&g_wbf[OFF_PWO + (n * 16 + lo) * 128 + kk * 32 + hi * 8];
            acc2[n] = __builtin_amdgcn_mfma_f32_16x16x32_bf16(a, b, acc2[n], 0, 0, 0);
        }
    }
#pragma unroll
    for (int n = 0; n < 4; ++n) {
        int col = n * 16 + lo;
#pragma unroll
        for (int r = 0; r < 4; ++r) {
            int row = w * 16 + hi * 4 + r;
            int obj = row0 + row;
            if (obj < NOBJ)
                out[(size_t)obj * 64 + col] = emb[(size_t)obj * 64 + col] + acc2[n][r];
        }
    }
}

// fallback update (reads f64 sums)
__global__ __launch_bounds__(256)
void update_mfma_f64(const float* __restrict__ emb, const double* __restrict__ ssum64,
                     const float* __restrict__ bi, const float* __restrict__ bo,
                     float* __restrict__ out) {
    __shared__ u16 uin[64 * 128];
    __shared__ u16 h[64 * 128];
    const int tid = threadIdx.x;
    const int w = tid >> 6, l = tid & 63, lo = l & 15, hi = l >> 4;
    const int row0 = blockIdx.x * 64;

    for (int i = tid; i < 64 * 128; i += 256) {
        int r = i >> 7, c = i & 127;
        int obj = row0 + r;
        float v = 0.f;
        if (obj < NOBJ) {
            if (c < 64) v = lse_from_sum(ssum64[(size_t)obj * 64 + c]);
            else v = emb[(size_t)obj * 64 + (c - 64)];
        }
        uin[i ^ ((r & 7) << 3)] = f2b(v);
    }
    __syncthreads();

    const int arow = w * 16 + lo;
    const int asw = (arow & 7) << 3;
    f32x4 acc[8];
#pragma unroll
    for (int n = 0; n < 8; ++n) { float b = bi[n * 16 + lo]; acc[n] = (f32x4){b, b, b, b}; }
#pragma unroll
    for (int kk = 0; kk < 4; ++kk) {
        bf16x8 a = *(const bf16x8*)&uin[(arow * 128 + kk * 32 + hi * 8) ^ asw];
#pragma unroll
        for (int n = 0; n < 8; ++n) {
            bf16x8 b = *(const bf16x8*)&g_wbf[OFF_PWI + (n * 16 + lo) * 128 + kk * 32 + hi * 8];
            acc[n] = __builtin_amdgcn_mfma_f32_16x16x32_bf16(a, b, acc[n], 0, 0, 0);
        }
    }
#pragma unroll
    for (int n = 0; n < 8; ++n) {
#pragma unroll
        for (int r = 0; r < 4; ++r) {
            int row = w * 16 + hi * 4 + r;
            int col = n * 16 + lo;
            h[(row * 128 + col) ^ ((row & 7) << 3)] = f2b(mish_fast(acc[n][r]));
        }
    }
    __syncthreads();
    f32x4 acc2[4];
#pragma unroll
    for (int n = 0; n < 4; ++n) { float b = bo[n * 16 + lo]; acc2[n] = (f32x4){b, b, b, b}; }
#pragma unroll
    for (int kk = 0; kk < 4; ++kk) {
        bf16x8 a = *(const bf16x8*)&h[(arow * 128 + kk * 32 + hi * 8) ^ asw];
#pragma unroll
        for (int n = 0; n < 4; ++n) {
            bf16x8 b = *(const bf16x8*)&g_wbf[OFF_PWO + (n * 16 + lo) * 128 + kk * 32 + hi * 8];
            acc2[n] = __builtin_amdgcn_mfma_f32_16x16x32_bf16(a, b, acc2[n], 0, 0, 0);
        }
    }
#pragma unroll
    for (int n = 0; n < 4; ++n) {
        int col = n * 16 + lo;
#pragma unroll
        for (int r = 0; r < 4; ++r) {
            int row = w * 16 + hi * 4 + r;
            int obj = row0 + row;
            if (obj < NOBJ)
                out[(size_t)obj * 64 + col] = emb[(size_t)obj * 64 + col] + acc2[n][r];
        }
    }
}

static inline size_t align256(size_t x) { return (x + 255) & ~(size_t)255; }

extern "C" void kernel_launch(void* const* d_in, const int* in_sizes, int n_in,
                              void* d_out, int out_size, void* d_ws, size_t ws_size,
                              hipStream_t stream) {
    const float* emb = (const float*)d_in[0];
    const int* iu = (const int*)d_in[1];
    const int* ib = (const int*)d_in[2];
    const int* it = (const int*)d_in[3];
    const float* uwi = (const float*)d_in[4];
    const float* ubi = (const float*)d_in[5];
    const float* uwo = (const float*)d_in[6];
    const float* ubo = (const float*)d_in[7];
    const float* bwi = (const float*)d_in[8];
    const float* bbi = (const float*)d_in[9];
    const float* bwo = (const float*)d_in[10];
    const float* bbo = (const float*)d_in[11];
    const float* twi = (const float*)d_in[12];
    const float* tbi = (const float*)d_in[13];
    const float* two_ = (const float*)d_in[14];
    const float* tbo = (const float*)d_in[15];
    const float* pwi = (const float*)d_in[16];
    const float* pbi = (const float*)d_in[17];
    const float* pwo = (const float*)d_in[18];
    const float* pbo = (const float*)d_in[19];

    const int nU = in_sizes[1];
    const int nB = in_sizes[2];
    const int nT = in_sizes[3];
    const int rowsU = nU;
    const int rowsB = nB / 2;
    const int rowsT = nT / 3;
    const long long NREF = (long long)nU + nB + nT;

    const size_t seg = (size_t)NOBJ * 64;
    const int gU = (rowsU + 63) / 64;
    const int gB = (rowsB + 63) / 64;
    const int gT = (rowsT + 63) / 64;
    const int nblkScan = (NOBJ + 255) / 256;
    const int gPrep = (NOBJ * 16 + 255) / 256;

    // ---- CSR workspace layout ----
    char* p = (char*)d_ws;
    u16* msgs = (u16*)p;        p += align256(2 * (size_t)NREF * 64);
    u32* counts = (u32*)p;      p += align256(4 * (size_t)NOBJ);
    u32* offs = (u32*)p;        p += align256(4 * (size_t)NOBJ);
    u32* cursor = (u32*)p;      p += align256(4 * (size_t)NOBJ);
    u32* bsum = (u32*)p;        p += align256(4 * 512);
    u32* slotByRef = (u32*)p;   p += align256(4 * (size_t)NREF);
    u16* emb_bf = (u16*)p;      p += align256(2 * seg);
    const size_t need = (size_t)(p - (char*)d_ws);

    if (ws_size >= need) {
        // ========== CSR path: sorted f16 msg writes, streaming aggregate, 0 fp atomics ==========
        prep_kernel<<<gPrep, 256, 0, stream>>>(uwi, uwo, bwi, bwo, twi, two_, pwi, pwo,
                                               emb, emb_bf, counts, cursor);
        int gRef = (int)((NREF + 255) / 256);
        hist_kernel<<<gRef, 256, 0, stream>>>(iu, nU, ib, nB, it, nT, counts);
        scan1_kernel<<<nblkScan, 256, 0, stream>>>(counts, offs, bsum);
        scan2_kernel<<<1, 512, 0, stream>>>(bsum, nblkScan);
        slot_kernel<<<gRef, 256, 0, stream>>>(iu, nU, ib, nB, it, nT, offs, bsum, cursor, slotByRef);

        rel_pass_mfma<64, 4, 3, OFF_UWI, OFF_UWO><<<gU, 256, 0, stream>>>(
            emb_bf, iu, rowsU, ubi, ubo, nullptr, msgs, slotByRef, 0LL);
        rel_pass_mfma<128, 4, 3, OFF_BWI, OFF_BWO><<<gB, 256, 0, stream>>>(
            emb_bf, ib, rowsB, bbi, bbo, nullptr, msgs, slotByRef, (long long)nU);
        rel_pass_mfma<192, 4, 3, OFF_TWI, OFF_TWO><<<gT, 256, 0, stream>>>(
            emb_bf, it, rowsT, tbi, tbo, nullptr, msgs, slotByRef, (long long)(nU + nB));

        agg_update<<<(NOBJ + 63) / 64, 256, 0, stream>>>(
            emb, msgs, offs, bsum, counts, pbi, pbo, (float*)d_out);
    } else {
        // ========== f64 single-pass fallback ==========
        double* ssum64 = (double*)d_ws;
        u16* emb_bf2 = (u16*)((char*)d_ws + seg * sizeof(double));
        prep_kernel<<<gPrep, 256, 0, stream>>>(uwi, uwo, bwi, bwo, twi, two_, pwi, pwo,
                                               emb, emb_bf2, nullptr, nullptr);
        hipMemsetAsync(ssum64, 0, seg * sizeof(double), stream);
        rel_pass_mfma<64, 4, 2, OFF_UWI, OFF_UWO><<<gU, 256, 0, stream>>>(
            emb_bf2, iu, rowsU, ubi, ubo, ssum64, nullptr, nullptr, 0);
        rel_pass_mfma<128, 4, 2, OFF_BWI, OFF_BWO><<<gB, 256, 0, stream>>>(
            emb_bf2, ib, rowsB, bbi, bbo, ssum64, nullptr, nullptr, 0);
        rel_pass_mfma<192, 4, 2, OFF_TWI, OFF_TWO><<<gT, 256, 0, stream>>>(
            emb_bf2, it, rowsT, tbi, tbo, ssum64, nullptr, nullptr, 0);
        update_mfma_f64<<<(NOBJ + 63) / 64, 256, 0, stream>>>(
            emb, ssum64, pbi, pbo, (float*)d_out);
    }
}

// Round 10
// 374.007 us; speedup vs baseline: 1.0415x; 1.0415x over previous
//
#include <hip/hip_runtime.h>
#include <math.h>

#define NOBJ 100000
#define SMOOTH 12.0f

typedef __attribute__((ext_vector_type(8))) short bf16x8;
typedef __attribute__((ext_vector_type(4))) float f32x4;
typedef unsigned short u16;
typedef unsigned int u32;
typedef unsigned long long u64;

// bf16 weight table
#define OFF_UWI 0
#define OFF_UWO 4096
#define OFF_BWI 8192
#define OFF_BWO 24576
#define OFF_TWI 40960
#define OFF_TWO 77824
#define OFF_PWI 114688
#define OFF_PWO 131072
#define WTOT    139264
__device__ u16 g_wbf[WTOT];

__device__ __forceinline__ u16 f2b(float x) {
    union { float f; u32 u; } v; v.f = x;
    u32 r = v.u + 0x7FFFu + ((v.u >> 16) & 1);  // RNE
    return (u16)(r >> 16);
}
__device__ __forceinline__ float b2f(u16 b) {
    union { u32 u; float f; } v; v.u = ((u32)b) << 16; return v.f;
}
__device__ __forceinline__ float mish_fast(float x) {
    float e = __expf(fminf(x, 15.f));
    float t = __builtin_fmaf(e, e, 2.f * e);
    return x * t * __builtin_amdgcn_rcpf(t + 2.f);
}
__device__ __forceinline__ double exp12_f64(float m) {
    float t = m * (SMOOTH * 1.4426950408889634f);
    float n = floorf(t);
    float f = exp2f(t - n);
    return ldexp((double)f, (int)n);
}
__device__ __forceinline__ float lse_from_sum(double S) {
    if (S == 0.0) return -3.0701134573253942f;  // log(1e-16)/12
    union { double d; u64 u; } vu; vu.d = S;
    int k = (int)((vu.u >> 52) & 0x7FF) - 1022;
    vu.u = (vu.u & 0x000FFFFFFFFFFFFFULL) | 0x3FE0000000000000ULL;
    float fr = (float)vu.d;
    return ((float)k + __log2f(fr)) * 0.057762265046662105f;  // *ln2/12
}

// weights -> bf16 table, emb -> bf16 table, zero counts/cursor
__global__ void prep_kernel(const float* __restrict__ uwi, const float* __restrict__ uwo,
                            const float* __restrict__ bwi, const float* __restrict__ bwo,
                            const float* __restrict__ twi, const float* __restrict__ two_,
                            const float* __restrict__ pwi, const float* __restrict__ pwo,
                            const float* __restrict__ emb, u16* __restrict__ emb_bf,
                            u32* __restrict__ counts, u32* __restrict__ cursor) {
    int i = blockIdx.x * 256 + threadIdx.x;
    if (i < WTOT) {
        const float* src; int off;
        if      (i < OFF_UWO) { src = uwi; off = OFF_UWI; }
        else if (i < OFF_BWI) { src = uwo; off = OFF_UWO; }
        else if (i < OFF_BWO) { src = bwi; off = OFF_BWI; }
        else if (i < OFF_TWI) { src = bwo; off = OFF_BWO; }
        else if (i < OFF_TWO) { src = twi; off = OFF_TWI; }
        else if (i < OFF_PWI) { src = two_; off = OFF_TWO; }
        else if (i < OFF_PWO) { src = pwi; off = OFF_PWI; }
        else                  { src = pwo; off = OFF_PWO; }
        g_wbf[i] = f2b(src[i - off]);
    }
    if (i < NOBJ * 16) {
        float4 v = ((const float4*)emb)[i];
        ushort4 o;
        o.x = f2b(v.x); o.y = f2b(v.y); o.z = f2b(v.z); o.w = f2b(v.w);
        ((ushort4*)emb_bf)[i] = o;
    }
    if (counts && i < NOBJ) { counts[i] = 0u; cursor[i] = 0u; }
}

__device__ __forceinline__ int lookup_obj(long long m,
                                          const int* __restrict__ iu, int nU,
                                          const int* __restrict__ ib, int nB,
                                          const int* __restrict__ it) {
    if (m < nU) return iu[m];
    m -= nU;
    if (m < nB) return ib[m];
    return it[m - nB];
}

// ---------- CSR build ----------
__global__ void hist_kernel(const int* __restrict__ iu, int nU,
                            const int* __restrict__ ib, int nB,
                            const int* __restrict__ it, int nT,
                            u32* __restrict__ counts) {
    long long t = (long long)blockIdx.x * 256 + threadIdx.x;
    if (t >= (long long)nU + nB + nT) return;
    atomicAdd(&counts[lookup_obj(t, iu, nU, ib, nB, it)], 1u);
}

__global__ void scan1_kernel(const u32* __restrict__ counts, u32* __restrict__ offs,
                             u32* __restrict__ bsum) {
    __shared__ u32 s[256];
    int t = threadIdx.x;
    int g = blockIdx.x * 256 + t;
    u32 v = (g < NOBJ) ? counts[g] : 0u;
    s[t] = v; __syncthreads();
    for (int off = 1; off < 256; off <<= 1) {
        u32 x = (t >= off) ? s[t - off] : 0u; __syncthreads();
        s[t] += x; __syncthreads();
    }
    if (g < NOBJ) offs[g] = s[t] - v;
    if (t == 255) bsum[blockIdx.x] = s[255];
}

__global__ void scan2_kernel(u32* __restrict__ bsum, int nblk) {
    __shared__ u32 s[512];
    int t = threadIdx.x;
    u32 v = (t < nblk) ? bsum[t] : 0u;
    s[t] = v; __syncthreads();
    for (int off = 1; off < 512; off <<= 1) {
        u32 x = (t >= off) ? s[t - off] : 0u; __syncthreads();
        s[t] += x; __syncthreads();
    }
    if (t < nblk) bsum[t] = s[t] - v;
}

__global__ void slot_kernel(const int* __restrict__ iu, int nU,
                            const int* __restrict__ ib, int nB,
                            const int* __restrict__ it, int nT,
                            const u32* __restrict__ offs, const u32* __restrict__ bsum,
                            u32* __restrict__ cursor, u32* __restrict__ slotByRef) {
    long long t = (long long)blockIdx.x * 256 + threadIdx.x;
    if (t >= (long long)nU + nB + nT) return;
    int obj = lookup_obj(t, iu, nU, ib, nB, it);
    u32 pos = atomicAdd(&cursor[obj], 1u);
    slotByRef[t] = offs[obj] + bsum[obj >> 8] + pos;
}

// ---------- fused relation MLP (LDS-staged weights) ----------
// xs: x -> h -> msg in place (strip-local). wlds: 64-k-col weight chunks, shared.
// MODE 2: f64 atomicAdd exp(12*m) | MODE 3: CSR slot-directed f16 msg write
template<int D, int MW, int MODE, int WOFF_I, int WOFF_O>
__global__ __launch_bounds__(64 * MW)
void rel_pass_mfma(const u16* __restrict__ emb_bf,
                   const int* __restrict__ idx, int nRows,
                   const float* __restrict__ bi, const float* __restrict__ bo,
                   double* __restrict__ ssum64,
                   u16* __restrict__ msgs_out, const u32* __restrict__ slotByRef,
                   long long baseRef) {
    constexpr int ARITY = D / 64;
    constexpr int NT = D / 16;
    constexpr int NSC = D / 64;       // 64-k-col stages per layer
    constexpr int M = MW * 16;
    __shared__ u16 xs[M * D];
    __shared__ u16 wlds[D * 64];
    __shared__ int objsm[M * ARITY];
    __shared__ u32 slotm[M * ARITY];

    const int tid = threadIdx.x;
    const int w = tid >> 6, l = tid & 63;
    const int lo = l & 15, hi = l >> 4;
    const int row0 = blockIdx.x * M;

    for (int i = tid; i < M * ARITY; i += 64 * MW) {
        int row = row0 + i / ARITY;
        bool ok = (row < nRows);
        objsm[i] = ok ? idx[(size_t)row * ARITY + i % ARITY] : -1;
        if (MODE == 3)
            slotm[i] = ok ? slotByRef[baseRef + (long long)row0 * ARITY + i] : 0xFFFFFFFFu;
    }
    __syncthreads();

    // bf16 gather: 16B per lane-iteration, XOR-swizzled LDS
    for (int i = tid; i < M * D / 8; i += 64 * MW) {
        int r = i / (D / 8), c8 = i % (D / 8);
        int obj = objsm[r * ARITY + (c8 >> 3)];
        bf16x8 v = {0, 0, 0, 0, 0, 0, 0, 0};
        if (obj >= 0) v = *(const bf16x8*)(emb_bf + (size_t)obj * 64 + (c8 & 7) * 8);
        *(bf16x8*)&xs[(r * D + c8 * 8) ^ ((r & 7) << 3)] = v;
    }

    f32x4 acc[NT];
    const int arow = w * 16 + lo;
    const int asw = (arow & 7) << 3;

    // ---- layer 1: y1 = x @ wi^T + bi ----
#pragma unroll
    for (int n = 0; n < NT; ++n) { float b = bi[n * 16 + lo]; acc[n] = (f32x4){b, b, b, b}; }
#pragma unroll
    for (int sc = 0; sc < NSC; ++sc) {
        __syncthreads();
        for (int i = tid; i < D * 8; i += 64 * MW) {
            int u = i * 8;
            int j = u >> 6;
            bf16x8 v = *(const bf16x8*)&g_wbf[WOFF_I + j * D + sc * 64 + (u & 63)];
            *(bf16x8*)&wlds[u ^ ((j & 7) << 3)] = v;
        }
        __syncthreads();
#pragma unroll
        for (int kkL = 0; kkL < 2; ++kkL) {
            bf16x8 a = *(const bf16x8*)&xs[(arow * D + (sc * 2 + kkL) * 32 + hi * 8) ^ asw];
#pragma unroll
            for (int n = 0; n < NT; ++n) {
                int j = n * 16 + lo;
                bf16x8 b = *(const bf16x8*)&wlds[(j * 64 + kkL * 32 + hi * 8) ^ ((j & 7) << 3)];
                acc[n] = __builtin_amdgcn_mfma_f32_16x16x32_bf16(a, b, acc[n], 0, 0, 0);
            }
        }
    }

    // mish -> own strip; fold residual x + bo into layer-2 acc init
#pragma unroll
    for (int n = 0; n < NT; ++n) {
        float bov = bo[n * 16 + lo];
#pragma unroll
        for (int r = 0; r < 4; ++r) {
            int row = w * 16 + hi * 4 + r;
            int col = n * 16 + lo;
            int sidx = (row * D + col) ^ ((row & 7) << 3);
            float xv = b2f(xs[sidx]);
            xs[sidx] = f2b(mish_fast(acc[n][r]));
            acc[n][r] = bov + xv;
        }
    }

    // ---- layer 2: m = h @ wo^T + (bo + x) ----
#pragma unroll
    for (int sc = 0; sc < NSC; ++sc) {
        __syncthreads();
        for (int i = tid; i < D * 8; i += 64 * MW) {
            int u = i * 8;
            int j = u >> 6;
            bf16x8 v = *(const bf16x8*)&g_wbf[WOFF_O + j * D + sc * 64 + (u & 63)];
            *(bf16x8*)&wlds[u ^ ((j & 7) << 3)] = v;
        }
        __syncthreads();
#pragma unroll
        for (int kkL = 0; kkL < 2; ++kkL) {
            bf16x8 a = *(const bf16x8*)&xs[(arow * D + (sc * 2 + kkL) * 32 + hi * 8) ^ asw];
#pragma unroll
            for (int n = 0; n < NT; ++n) {
                int j = n * 16 + lo;
                bf16x8 b = *(const bf16x8*)&wlds[(j * 64 + kkL * 32 + hi * 8) ^ ((j & 7) << 3)];
                acc[n] = __builtin_amdgcn_mfma_f32_16x16x32_bf16(a, b, acc[n], 0, 0, 0);
            }
        }
    }

    if (MODE == 3) {
#pragma unroll
        for (int n = 0; n < NT; ++n) {
            int col = n * 16 + lo;
#pragma unroll
            for (int r = 0; r < 4; ++r) {
                int row = w * 16 + hi * 4 + r;
                _Float16 hv = (_Float16)acc[n][r];
                xs[(row * D + col) ^ ((row & 7) << 3)] = *(u16*)&hv;
            }
        }
        __syncthreads();
        for (int i = tid; i < M * D / 8; i += 64 * MW) {
            int u = i * 8;
            int row = u / D, off = u - row * D;
            u32 slot = slotm[row * ARITY + (off >> 6)];
            if (slot == 0xFFFFFFFFu) continue;
            *(bf16x8*)(msgs_out + (size_t)slot * 64 + (off & 63)) =
                *(const bf16x8*)&xs[u ^ ((row & 7) << 3)];
        }
    } else {
#pragma unroll
        for (int n = 0; n < NT; ++n) {
            int col = n * 16 + lo;
#pragma unroll
            for (int r = 0; r < 4; ++r) {
                int row = w * 16 + hi * 4 + r;
                int obj = objsm[row * ARITY + (col >> 6)];
                if (obj < 0) continue;
                unsafeAtomicAdd(&ssum64[(size_t)obj * 64 + (col & 63)], exp12_f64(acc[n][r]));
            }
        }
    }
}

// ---------- aggregate: one wave per object, lane = column, zero LDS/shuffles ----------
__global__ __launch_bounds__(256)
void agg_kernel(const u16* __restrict__ msgs,
                const u32* __restrict__ offs, const u32* __restrict__ bsum,
                const u32* __restrict__ counts,
                float* __restrict__ lse_out) {
    int o = blockIdx.x * 4 + (threadIdx.x >> 6);
    int l = threadIdx.x & 63;
    if (o >= NOBJ) return;
    u32 off = offs[o] + bsum[o >> 8];
    u32 n = counts[o];
    const u16* mrow = msgs + (size_t)off * 64 + l;
    double S0 = 0.0, S1 = 0.0, S2 = 0.0, S3 = 0.0;
    u32 j = 0;
    for (; j + 4 <= n; j += 4) {
        u16 h0 = mrow[(size_t)(j + 0) * 64];
        u16 h1 = mrow[(size_t)(j + 1) * 64];
        u16 h2 = mrow[(size_t)(j + 2) * 64];
        u16 h3 = mrow[(size_t)(j + 3) * 64];
        S0 += exp12_f64((float)(*(const _Float16*)&h0));
        S1 += exp12_f64((float)(*(const _Float16*)&h1));
        S2 += exp12_f64((float)(*(const _Float16*)&h2));
        S3 += exp12_f64((float)(*(const _Float16*)&h3));
    }
    for (; j < n; ++j) {
        u16 h = mrow[(size_t)j * 64];
        S0 += exp12_f64((float)(*(const _Float16*)&h));
    }
    lse_out[(size_t)o * 64 + l] = lse_from_sum((S0 + S1) + (S2 + S3));
}

// ---------- update MLP reading f32 LSE (lsein may alias out; reads precede writes per block) ----------
__global__ __launch_bounds__(256)
void update_from_lse(const float* __restrict__ emb, const float* lsein,
                     const float* __restrict__ bi, const float* __restrict__ bo,
                     float* out) {
    __shared__ u16 uin[64 * 128];
    __shared__ u16 h[64 * 128];
    const int tid = threadIdx.x;
    const int w = tid >> 6, l = tid & 63, lo = l & 15, hi = l >> 4;
    const int row0 = blockIdx.x * 64;

    for (int i = tid; i < 64 * 128; i += 256) {
        int r = i >> 7, c = i & 127;
        int obj = row0 + r;
        float v = 0.f;
        if (obj < NOBJ) {
            if (c < 64) v = lsein[(size_t)obj * 64 + c];
            else v = emb[(size_t)obj * 64 + (c - 64)];
        }
        uin[i ^ ((r & 7) << 3)] = f2b(v);
    }
    __syncthreads();

    const int arow = w * 16 + lo;
    const int asw = (arow & 7) << 3;
    f32x4 acc[8];
#pragma unroll
    for (int n = 0; n < 8; ++n) { float b = bi[n * 16 + lo]; acc[n] = (f32x4){b, b, b, b}; }
#pragma unroll
    for (int kk = 0; kk < 4; ++kk) {
        bf16x8 a = *(const bf16x8*)&uin[(arow * 128 + kk * 32 + hi * 8) ^ asw];
#pragma unroll
        for (int n = 0; n < 8; ++n) {
            bf16x8 b = *(const bf16x8*)&g_wbf[OFF_PWI + (n * 16 + lo) * 128 + kk * 32 + hi * 8];
            acc[n] = __builtin_amdgcn_mfma_f32_16x16x32_bf16(a, b, acc[n], 0, 0, 0);
        }
    }
#pragma unroll
    for (int n = 0; n < 8; ++n) {
#pragma unroll
        for (int r = 0; r < 4; ++r) {
            int row = w * 16 + hi * 4 + r;
            int col = n * 16 + lo;
            h[(row * 128 + col) ^ ((row & 7) << 3)] = f2b(mish_fast(acc[n][r]));
        }
    }
    __syncthreads();
    f32x4 acc2[4];
#pragma unroll
    for (int n = 0; n < 4; ++n) { float b = bo[n * 16 + lo]; acc2[n] = (f32x4){b, b, b, b}; }
#pragma unroll
    for (int kk = 0; kk < 4; ++kk) {
        bf16x8 a = *(const bf16x8*)&h[(arow * 128 + kk * 32 + hi * 8) ^ asw];
#pragma unroll
        for (int n = 0; n < 4; ++n) {
            bf16x8 b = *(const bf16x8*)&g_wbf[OFF_PWO + (n * 16 + lo) * 128 + kk * 32 + hi * 8];
            acc2[n] = __builtin_amdgcn_mfma_f32_16x16x32_bf16(a, b, acc2[n], 0, 0, 0);
        }
    }
#pragma unroll
    for (int n = 0; n < 4; ++n) {
        int col = n * 16 + lo;
#pragma unroll
        for (int r = 0; r < 4; ++r) {
            int row = w * 16 + hi * 4 + r;
            int obj = row0 + row;
            if (obj < NOBJ)
                out[(size_t)obj * 64 + col] = emb[(size_t)obj * 64 + col] + acc2[n][r];
        }
    }
}

// fallback update (reads f64 sums)
__global__ __launch_bounds__(256)
void update_mfma_f64(const float* __restrict__ emb, const double* __restrict__ ssum64,
                     const float* __restrict__ bi, const float* __restrict__ bo,
                     float* __restrict__ out) {
    __shared__ u16 uin[64 * 128];
    __shared__ u16 h[64 * 128];
    const int tid = threadIdx.x;
    const int w = tid >> 6, l = tid & 63, lo = l & 15, hi = l >> 4;
    const int row0 = blockIdx.x * 64;

    for (int i = tid; i < 64 * 128; i += 256) {
        int r = i >> 7, c = i & 127;
        int obj = row0 + r;
        float v = 0.f;
        if (obj < NOBJ) {
            if (c < 64) v = lse_from_sum(ssum64[(size_t)obj * 64 + c]);
            else v = emb[(size_t)obj * 64 + (c - 64)];
        }
        uin[i ^ ((r & 7) << 3)] = f2b(v);
    }
    __syncthreads();

    const int arow = w * 16 + lo;
    const int asw = (arow & 7) << 3;
    f32x4 acc[8];
#pragma unroll
    for (int n = 0; n < 8; ++n) { float b = bi[n * 16 + lo]; acc[n] = (f32x4){b, b, b, b}; }
#pragma unroll
    for (int kk = 0; kk < 4; ++kk) {
        bf16x8 a = *(const bf16x8*)&uin[(arow * 128 + kk * 32 + hi * 8) ^ asw];
#pragma unroll
        for (int n = 0; n < 8; ++n) {
            bf16x8 b = *(const bf16x8*)&g_wbf[OFF_PWI + (n * 16 + lo) * 128 + kk * 32 + hi * 8];
            acc[n] = __builtin_amdgcn_mfma_f32_16x16x32_bf16(a, b, acc[n], 0, 0, 0);
        }
    }
#pragma unroll
    for (int n = 0; n < 8; ++n) {
#pragma unroll
        for (int r = 0; r < 4; ++r) {
            int row = w * 16 + hi * 4 + r;
            int col = n * 16 + lo;
            h[(row * 128 + col) ^ ((row & 7) << 3)] = f2b(mish_fast(acc[n][r]));
        }
    }
    __syncthreads();
    f32x4 acc2[4];
#pragma unroll
    for (int n = 0; n < 4; ++n) { float b = bo[n * 16 + lo]; acc2[n] = (f32x4){b, b, b, b}; }
#pragma unroll
    for (int kk = 0; kk < 4; ++kk) {
        bf16x8 a = *(const bf16x8*)&h[(arow * 128 + kk * 32 + hi * 8) ^ asw];
#pragma unroll
        for (int n = 0; n < 4; ++n) {
            bf16x8 b = *(const bf16x8*)&g_wbf[OFF_PWO + (n * 16 + lo) * 128 + kk * 32 + hi * 8];
            acc2[n] = __builtin_amdgcn_mfma_f32_16x16x32_bf16(a, b, acc2[n], 0, 0, 0);
        }
    }
#pragma unroll
    for (int n = 0; n < 4; ++n) {
        int col = n * 16 + lo;
#pragma unroll
        for (int r = 0; r < 4; ++r) {
            int row = w * 16 + hi * 4 + r;
            int obj = row0 + row;
            if (obj < NOBJ)
                out[(size_t)obj * 64 + col] = emb[(size_t)obj * 64 + col] + acc2[n][r];
        }
    }
}

static inline size_t align256(size_t x) { return (x + 255) & ~(size_t)255; }

extern "C" void kernel_launch(void* const* d_in, const int* in_sizes, int n_in,
                              void* d_out, int out_size, void* d_ws, size_t ws_size,
                              hipStream_t stream) {
    const float* emb = (const float*)d_in[0];
    const int* iu = (const int*)d_in[1];
    const int* ib = (const int*)d_in[2];
    const int* it = (const int*)d_in[3];
    const float* uwi = (const float*)d_in[4];
    const float* ubi = (const float*)d_in[5];
    const float* uwo = (const float*)d_in[6];
    const float* ubo = (const float*)d_in[7];
    const float* bwi = (const float*)d_in[8];
    const float* bbi = (const float*)d_in[9];
    const float* bwo = (const float*)d_in[10];
    const float* bbo = (const float*)d_in[11];
    const float* twi = (const float*)d_in[12];
    const float* tbi = (const float*)d_in[13];
    const float* two_ = (const float*)d_in[14];
    const float* tbo = (const float*)d_in[15];
    const float* pwi = (const float*)d_in[16];
    const float* pbi = (const float*)d_in[17];
    const float* pwo = (const float*)d_in[18];
    const float* pbo = (const float*)d_in[19];

    const int nU = in_sizes[1];
    const int nB = in_sizes[2];
    const int nT = in_sizes[3];
    const int rowsU = nU;
    const int rowsB = nB / 2;
    const int rowsT = nT / 3;
    const long long NREF = (long long)nU + nB + nT;

    const size_t seg = (size_t)NOBJ * 64;
    const int gU = (rowsU + 63) / 64;
    const int gB = (rowsB + 63) / 64;
    const int gT = (rowsT + 63) / 64;
    const int nblkScan = (NOBJ + 255) / 256;
    const int gPrep = (NOBJ * 16 + 255) / 256;

    // ---- CSR workspace layout ----
    char* p = (char*)d_ws;
    u16* msgs = (u16*)p;        p += align256(2 * (size_t)NREF * 64);
    u32* counts = (u32*)p;      p += align256(4 * (size_t)NOBJ);
    u32* offs = (u32*)p;        p += align256(4 * (size_t)NOBJ);
    u32* cursor = (u32*)p;      p += align256(4 * (size_t)NOBJ);
    u32* bsum = (u32*)p;        p += align256(4 * 512);
    u32* slotByRef = (u32*)p;   p += align256(4 * (size_t)NREF);
    u16* emb_bf = (u16*)p;      p += align256(2 * seg);
    const size_t need = (size_t)(p - (char*)d_ws);

    if (ws_size >= need) {
        // ========== CSR path: sorted f16 msg writes, streaming aggregate, 0 fp atomics ==========
        prep_kernel<<<gPrep, 256, 0, stream>>>(uwi, uwo, bwi, bwo, twi, two_, pwi, pwo,
                                               emb, emb_bf, counts, cursor);
        int gRef = (int)((NREF + 255) / 256);
        hist_kernel<<<gRef, 256, 0, stream>>>(iu, nU, ib, nB, it, nT, counts);
        scan1_kernel<<<nblkScan, 256, 0, stream>>>(counts, offs, bsum);
        scan2_kernel<<<1, 512, 0, stream>>>(bsum, nblkScan);
        slot_kernel<<<gRef, 256, 0, stream>>>(iu, nU, ib, nB, it, nT, offs, bsum, cursor, slotByRef);

        rel_pass_mfma<64, 4, 3, OFF_UWI, OFF_UWO><<<gU, 256, 0, stream>>>(
            emb_bf, iu, rowsU, ubi, ubo, nullptr, msgs, slotByRef, 0LL);
        rel_pass_mfma<128, 4, 3, OFF_BWI, OFF_BWO><<<gB, 256, 0, stream>>>(
            emb_bf, ib, rowsB, bbi, bbo, nullptr, msgs, slotByRef, (long long)nU);
        rel_pass_mfma<192, 4, 3, OFF_TWI, OFF_TWO><<<gT, 256, 0, stream>>>(
            emb_bf, it, rowsT, tbi, tbo, nullptr, msgs, slotByRef, (long long)(nU + nB));

        // LSE buffer lives in d_out (update reads each row before writing it)
        float* lsebuf = (float*)d_out;
        agg_kernel<<<(NOBJ + 3) / 4, 256, 0, stream>>>(msgs, offs, bsum, counts, lsebuf);
        update_from_lse<<<(NOBJ + 63) / 64, 256, 0, stream>>>(
            emb, lsebuf, pbi, pbo, (float*)d_out);
    } else {
        // ========== f64 single-pass fallback ==========
        double* ssum64 = (double*)d_ws;
        u16* emb_bf2 = (u16*)((char*)d_ws + seg * sizeof(double));
        prep_kernel<<<gPrep, 256, 0, stream>>>(uwi, uwo, bwi, bwo, twi, two_, pwi, pwo,
                                               emb, emb_bf2, nullptr, nullptr);
        hipMemsetAsync(ssum64, 0, seg * sizeof(double), stream);
        rel_pass_mfma<64, 4, 2, OFF_UWI, OFF_UWO><<<gU, 256, 0, stream>>>(
            emb_bf2, iu, rowsU, ubi, ubo, ssum64, nullptr, nullptr, 0);
        rel_pass_mfma<128, 4, 2, OFF_BWI, OFF_BWO><<<gB, 256, 0, stream>>>(
            emb_bf2, ib, rowsB, bbi, bbo, ssum64, nullptr, nullptr, 0);
        rel_pass_mfma<192, 4, 2, OFF_TWI, OFF_TWO><<<gT, 256, 0, stream>>>(
            emb_bf2, it, rowsT, tbi, tbo, ssum64, nullptr, nullptr, 0);
        update_mfma_f64<<<(NOBJ + 63) / 64, 256, 0, stream>>>(
            emb, ssum64, pbi, pbo, (float*)d_out);
    }
}

// Round 11
// 361.509 us; speedup vs baseline: 1.0775x; 1.0346x over previous
//
#include <hip/hip_runtime.h>
#include <math.h>

#define NOBJ 100000
#define SMOOTH 12.0f

typedef __attribute__((ext_vector_type(8))) short bf16x8;
typedef __attribute__((ext_vector_type(4))) float f32x4;
typedef unsigned short u16;
typedef unsigned int u32;
typedef unsigned long long u64;

// bf16 weight table
#define OFF_UWI 0
#define OFF_UWO 4096
#define OFF_BWI 8192
#define OFF_BWO 24576
#define OFF_TWI 40960
#define OFF_TWO 77824
#define OFF_PWI 114688
#define OFF_PWO 131072
#define WTOT    139264
__device__ u16 g_wbf[WTOT];

__device__ __forceinline__ u16 f2b(float x) {
    union { float f; u32 u; } v; v.f = x;
    u32 r = v.u + 0x7FFFu + ((v.u >> 16) & 1);  // RNE
    return (u16)(r >> 16);
}
__device__ __forceinline__ float b2f(u16 b) {
    union { u32 u; float f; } v; v.u = ((u32)b) << 16; return v.f;
}
__device__ __forceinline__ float mish_fast(float x) {
    float e = __expf(fminf(x, 15.f));
    float t = __builtin_fmaf(e, e, 2.f * e);
    return x * t * __builtin_amdgcn_rcpf(t + 2.f);
}
__device__ __forceinline__ double exp12_f64(float m) {
    float t = m * (SMOOTH * 1.4426950408889634f);
    float n = floorf(t);
    float f = exp2f(t - n);
    return ldexp((double)f, (int)n);
}
__device__ __forceinline__ float lse_from_sum(double S) {
    if (S == 0.0) return -3.0701134573253942f;  // log(1e-16)/12
    union { double d; u64 u; } vu; vu.d = S;
    int k = (int)((vu.u >> 52) & 0x7FF) - 1022;
    vu.u = (vu.u & 0x000FFFFFFFFFFFFFULL) | 0x3FE0000000000000ULL;
    float fr = (float)vu.d;
    return ((float)k + __log2f(fr)) * 0.057762265046662105f;  // *ln2/12
}

// weights -> bf16 table, emb -> bf16 table, zero counts/cursor
__global__ void prep_kernel(const float* __restrict__ uwi, const float* __restrict__ uwo,
                            const float* __restrict__ bwi, const float* __restrict__ bwo,
                            const float* __restrict__ twi, const float* __restrict__ two_,
                            const float* __restrict__ pwi, const float* __restrict__ pwo,
                            const float* __restrict__ emb, u16* __restrict__ emb_bf,
                            u32* __restrict__ counts, u32* __restrict__ cursor) {
    int i = blockIdx.x * 256 + threadIdx.x;
    if (i < WTOT) {
        const float* src; int off;
        if      (i < OFF_UWO) { src = uwi; off = OFF_UWI; }
        else if (i < OFF_BWI) { src = uwo; off = OFF_UWO; }
        else if (i < OFF_BWO) { src = bwi; off = OFF_BWI; }
        else if (i < OFF_TWI) { src = bwo; off = OFF_BWO; }
        else if (i < OFF_TWO) { src = twi; off = OFF_TWI; }
        else if (i < OFF_PWI) { src = two_; off = OFF_TWO; }
        else if (i < OFF_PWO) { src = pwi; off = OFF_PWI; }
        else                  { src = pwo; off = OFF_PWO; }
        g_wbf[i] = f2b(src[i - off]);
    }
    if (i < NOBJ * 16) {
        float4 v = ((const float4*)emb)[i];
        ushort4 o;
        o.x = f2b(v.x); o.y = f2b(v.y); o.z = f2b(v.z); o.w = f2b(v.w);
        ((ushort4*)emb_bf)[i] = o;
    }
    if (counts && i < NOBJ) { counts[i] = 0u; cursor[i] = 0u; }
}

__device__ __forceinline__ int lookup_obj(long long m,
                                          const int* __restrict__ iu, int nU,
                                          const int* __restrict__ ib, int nB,
                                          const int* __restrict__ it) {
    if (m < nU) return iu[m];
    m -= nU;
    if (m < nB) return ib[m];
    return it[m - nB];
}

// ---------- CSR build ----------
__global__ void hist_kernel(const int* __restrict__ iu, int nU,
                            const int* __restrict__ ib, int nB,
                            const int* __restrict__ it, int nT,
                            u32* __restrict__ counts) {
    long long t = (long long)blockIdx.x * 256 + threadIdx.x;
    if (t >= (long long)nU + nB + nT) return;
    atomicAdd(&counts[lookup_obj(t, iu, nU, ib, nB, it)], 1u);
}

__global__ void scan1_kernel(const u32* __restrict__ counts, u32* __restrict__ offs,
                             u32* __restrict__ bsum) {
    __shared__ u32 s[256];
    int t = threadIdx.x;
    int g = blockIdx.x * 256 + t;
    u32 v = (g < NOBJ) ? counts[g] : 0u;
    s[t] = v; __syncthreads();
    for (int off = 1; off < 256; off <<= 1) {
        u32 x = (t >= off) ? s[t - off] : 0u; __syncthreads();
        s[t] += x; __syncthreads();
    }
    if (g < NOBJ) offs[g] = s[t] - v;
    if (t == 255) bsum[blockIdx.x] = s[255];
}

__global__ void scan2_kernel(u32* __restrict__ bsum, int nblk) {
    __shared__ u32 s[512];
    int t = threadIdx.x;
    u32 v = (t < nblk) ? bsum[t] : 0u;
    s[t] = v; __syncthreads();
    for (int off = 1; off < 512; off <<= 1) {
        u32 x = (t >= off) ? s[t - off] : 0u; __syncthreads();
        s[t] += x; __syncthreads();
    }
    if (t < nblk) bsum[t] = s[t] - v;
}

__global__ void slot_kernel(const int* __restrict__ iu, int nU,
                            const int* __restrict__ ib, int nB,
                            const int* __restrict__ it, int nT,
                            const u32* __restrict__ offs, const u32* __restrict__ bsum,
                            u32* __restrict__ cursor, u32* __restrict__ slotByRef) {
    long long t = (long long)blockIdx.x * 256 + threadIdx.x;
    if (t >= (long long)nU + nB + nT) return;
    int obj = lookup_obj(t, iu, nU, ib, nB, it);
    u32 pos = atomicAdd(&cursor[obj], 1u);
    slotByRef[t] = offs[obj] + bsum[obj >> 8] + pos;
}

// ---------- fused relation MLP (LDS-staged weights, 8-wave blocks) ----------
// xs: x -> h -> msg in place (strip-local). wlds: 64-k-col weight chunks, shared.
// MODE 2: f64 atomicAdd exp(12*m) | MODE 3: CSR slot-directed f16 msg write
template<int D, int MW, int MODE, int WOFF_I, int WOFF_O>
__global__ __launch_bounds__(64 * MW)
void rel_pass_mfma(const u16* __restrict__ emb_bf,
                   const int* __restrict__ idx, int nRows,
                   const float* __restrict__ bi, const float* __restrict__ bo,
                   double* __restrict__ ssum64,
                   u16* __restrict__ msgs_out, const u32* __restrict__ slotByRef,
                   long long baseRef) {
    constexpr int ARITY = D / 64;
    constexpr int NT = D / 16;
    constexpr int NSC = D / 64;       // 64-k-col stages per layer
    constexpr int M = MW * 16;
    __shared__ u16 xs[M * D];
    __shared__ u16 wlds[D * 64];
    __shared__ int objsm[M * ARITY];
    __shared__ u32 slotm[M * ARITY];

    const int tid = threadIdx.x;
    const int w = tid >> 6, l = tid & 63;
    const int lo = l & 15, hi = l >> 4;
    const int row0 = blockIdx.x * M;

    for (int i = tid; i < M * ARITY; i += 64 * MW) {
        int row = row0 + i / ARITY;
        bool ok = (row < nRows);
        objsm[i] = ok ? idx[(size_t)row * ARITY + i % ARITY] : -1;
        if (MODE == 3)
            slotm[i] = ok ? slotByRef[baseRef + (long long)row0 * ARITY + i] : 0xFFFFFFFFu;
    }
    __syncthreads();

    // bf16 gather: 16B per lane-iteration, XOR-swizzled LDS
    for (int i = tid; i < M * D / 8; i += 64 * MW) {
        int r = i / (D / 8), c8 = i % (D / 8);
        int obj = objsm[r * ARITY + (c8 >> 3)];
        bf16x8 v = {0, 0, 0, 0, 0, 0, 0, 0};
        if (obj >= 0) v = *(const bf16x8*)(emb_bf + (size_t)obj * 64 + (c8 & 7) * 8);
        *(bf16x8*)&xs[(r * D + c8 * 8) ^ ((r & 7) << 3)] = v;
    }

    f32x4 acc[NT];
    const int arow = w * 16 + lo;
    const int asw = (arow & 7) << 3;

    // ---- layer 1: y1 = x @ wi^T + bi ----
#pragma unroll
    for (int n = 0; n < NT; ++n) { float b = bi[n * 16 + lo]; acc[n] = (f32x4){b, b, b, b}; }
#pragma unroll
    for (int sc = 0; sc < NSC; ++sc) {
        __syncthreads();
        for (int i = tid; i < D * 8; i += 64 * MW) {
            int u = i * 8;
            int j = u >> 6;
            bf16x8 v = *(const bf16x8*)&g_wbf[WOFF_I + j * D + sc * 64 + (u & 63)];
            *(bf16x8*)&wlds[u ^ ((j & 7) << 3)] = v;
        }
        __syncthreads();
#pragma unroll
        for (int kkL = 0; kkL < 2; ++kkL) {
            bf16x8 a = *(const bf16x8*)&xs[(arow * D + (sc * 2 + kkL) * 32 + hi * 8) ^ asw];
#pragma unroll
            for (int n = 0; n < NT; ++n) {
                int j = n * 16 + lo;
                bf16x8 b = *(const bf16x8*)&wlds[(j * 64 + kkL * 32 + hi * 8) ^ ((j & 7) << 3)];
                acc[n] = __builtin_amdgcn_mfma_f32_16x16x32_bf16(a, b, acc[n], 0, 0, 0);
            }
        }
    }

    // mish -> own strip; fold residual x + bo into layer-2 acc init
#pragma unroll
    for (int n = 0; n < NT; ++n) {
        float bov = bo[n * 16 + lo];
#pragma unroll
        for (int r = 0; r < 4; ++r) {
            int row = w * 16 + hi * 4 + r;
            int col = n * 16 + lo;
            int sidx = (row * D + col) ^ ((row & 7) << 3);
            float xv = b2f(xs[sidx]);
            xs[sidx] = f2b(mish_fast(acc[n][r]));
            acc[n][r] = bov + xv;
        }
    }

    // ---- layer 2: m = h @ wo^T + (bo + x) ----
#pragma unroll
    for (int sc = 0; sc < NSC; ++sc) {
        __syncthreads();
        for (int i = tid; i < D * 8; i += 64 * MW) {
            int u = i * 8;
            int j = u >> 6;
            bf16x8 v = *(const bf16x8*)&g_wbf[WOFF_O + j * D + sc * 64 + (u & 63)];
            *(bf16x8*)&wlds[u ^ ((j & 7) << 3)] = v;
        }
        __syncthreads();
#pragma unroll
        for (int kkL = 0; kkL < 2; ++kkL) {
            bf16x8 a = *(const bf16x8*)&xs[(arow * D + (sc * 2 + kkL) * 32 + hi * 8) ^ asw];
#pragma unroll
            for (int n = 0; n < NT; ++n) {
                int j = n * 16 + lo;
                bf16x8 b = *(const bf16x8*)&wlds[(j * 64 + kkL * 32 + hi * 8) ^ ((j & 7) << 3)];
                acc[n] = __builtin_amdgcn_mfma_f32_16x16x32_bf16(a, b, acc[n], 0, 0, 0);
            }
        }
    }

    if (MODE == 3) {
#pragma unroll
        for (int n = 0; n < NT; ++n) {
            int col = n * 16 + lo;
#pragma unroll
            for (int r = 0; r < 4; ++r) {
                int row = w * 16 + hi * 4 + r;
                _Float16 hv = (_Float16)acc[n][r];
                xs[(row * D + col) ^ ((row & 7) << 3)] = *(u16*)&hv;
            }
        }
        __syncthreads();
        for (int i = tid; i < M * D / 8; i += 64 * MW) {
            int u = i * 8;
            int row = u / D, off = u - row * D;
            u32 slot = slotm[row * ARITY + (off >> 6)];
            if (slot == 0xFFFFFFFFu) continue;
            *(bf16x8*)(msgs_out + (size_t)slot * 64 + (off & 63)) =
                *(const bf16x8*)&xs[u ^ ((row & 7) << 3)];
        }
    } else {
#pragma unroll
        for (int n = 0; n < NT; ++n) {
            int col = n * 16 + lo;
#pragma unroll
            for (int r = 0; r < 4; ++r) {
                int row = w * 16 + hi * 4 + r;
                int obj = objsm[row * ARITY + (col >> 6)];
                if (obj < 0) continue;
                unsafeAtomicAdd(&ssum64[(size_t)obj * 64 + (col & 63)], exp12_f64(acc[n][r]));
            }
        }
    }
}

// ---------- aggregate: one wave per object, lane = column, zero LDS/shuffles ----------
__global__ __launch_bounds__(256)
void agg_kernel(const u16* __restrict__ msgs,
                const u32* __restrict__ offs, const u32* __restrict__ bsum,
                const u32* __restrict__ counts,
                float* __restrict__ lse_out) {
    int o = blockIdx.x * 4 + (threadIdx.x >> 6);
    int l = threadIdx.x & 63;
    if (o >= NOBJ) return;
    u32 off = offs[o] + bsum[o >> 8];
    u32 n = counts[o];
    const u16* mrow = msgs + (size_t)off * 64 + l;
    double S0 = 0.0, S1 = 0.0, S2 = 0.0, S3 = 0.0;
    u32 j = 0;
    for (; j + 4 <= n; j += 4) {
        u16 h0 = mrow[(size_t)(j + 0) * 64];
        u16 h1 = mrow[(size_t)(j + 1) * 64];
        u16 h2 = mrow[(size_t)(j + 2) * 64];
        u16 h3 = mrow[(size_t)(j + 3) * 64];
        S0 += exp12_f64((float)(*(const _Float16*)&h0));
        S1 += exp12_f64((float)(*(const _Float16*)&h1));
        S2 += exp12_f64((float)(*(const _Float16*)&h2));
        S3 += exp12_f64((float)(*(const _Float16*)&h3));
    }
    for (; j < n; ++j) {
        u16 h = mrow[(size_t)j * 64];
        S0 += exp12_f64((float)(*(const _Float16*)&h));
    }
    lse_out[(size_t)o * 64 + l] = lse_from_sum((S0 + S1) + (S2 + S3));
}

// ---------- update MLP reading f32 LSE (lsein may alias out; reads precede writes per block) ----------
__global__ __launch_bounds__(256)
void update_from_lse(const float* __restrict__ emb, const float* lsein,
                     const float* __restrict__ bi, const float* __restrict__ bo,
                     float* out) {
    __shared__ u16 uin[64 * 128];
    __shared__ u16 h[64 * 128];
    const int tid = threadIdx.x;
    const int w = tid >> 6, l = tid & 63, lo = l & 15, hi = l >> 4;
    const int row0 = blockIdx.x * 64;

    for (int i = tid; i < 64 * 128; i += 256) {
        int r = i >> 7, c = i & 127;
        int obj = row0 + r;
        float v = 0.f;
        if (obj < NOBJ) {
            if (c < 64) v = lsein[(size_t)obj * 64 + c];
            else v = emb[(size_t)obj * 64 + (c - 64)];
        }
        uin[i ^ ((r & 7) << 3)] = f2b(v);
    }
    __syncthreads();

    const int arow = w * 16 + lo;
    const int asw = (arow & 7) << 3;
    f32x4 acc[8];
#pragma unroll
    for (int n = 0; n < 8; ++n) { float b = bi[n * 16 + lo]; acc[n] = (f32x4){b, b, b, b}; }
#pragma unroll
    for (int kk = 0; kk < 4; ++kk) {
        bf16x8 a = *(const bf16x8*)&uin[(arow * 128 + kk * 32 + hi * 8) ^ asw];
#pragma unroll
        for (int n = 0; n < 8; ++n) {
            bf16x8 b = *(const bf16x8*)&g_wbf[OFF_PWI + (n * 16 + lo) * 128 + kk * 32 + hi * 8];
            acc[n] = __builtin_amdgcn_mfma_f32_16x16x32_bf16(a, b, acc[n], 0, 0, 0);
        }
    }
#pragma unroll
    for (int n = 0; n < 8; ++n) {
#pragma unroll
        for (int r = 0; r < 4; ++r) {
            int row = w * 16 + hi * 4 + r;
            int col = n * 16 + lo;
            h[(row * 128 + col) ^ ((row & 7) << 3)] = f2b(mish_fast(acc[n][r]));
        }
    }
    __syncthreads();
    f32x4 acc2[4];
#pragma unroll
    for (int n = 0; n < 4; ++n) { float b = bo[n * 16 + lo]; acc2[n] = (f32x4){b, b, b, b}; }
#pragma unroll
    for (int kk = 0; kk < 4; ++kk) {
        bf16x8 a = *(const bf16x8*)&h[(arow * 128 + kk * 32 + hi * 8) ^ asw];
#pragma unroll
        for (int n = 0; n < 4; ++n) {
            bf16x8 b = *(const bf16x8*)&g_wbf[OFF_PWO + (n * 16 + lo) * 128 + kk * 32 + hi * 8];
            acc2[n] = __builtin_amdgcn_mfma_f32_16x16x32_bf16(a, b, acc2[n], 0, 0, 0);
        }
    }
#pragma unroll
    for (int n = 0; n < 4; ++n) {
        int col = n * 16 + lo;
#pragma unroll
        for (int r = 0; r < 4; ++r) {
            int row = w * 16 + hi * 4 + r;
            int obj = row0 + row;
            if (obj < NOBJ)
                out[(size_t)obj * 64 + col] = emb[(size_t)obj * 64 + col] + acc2[n][r];
        }
    }
}

// fallback update (reads f64 sums)
__global__ __launch_bounds__(256)
void update_mfma_f64(const float* __restrict__ emb, const double* __restrict__ ssum64,
                     const float* __restrict__ bi, const float* __restrict__ bo,
                     float* __restrict__ out) {
    __shared__ u16 uin[64 * 128];
    __shared__ u16 h[64 * 128];
    const int tid = threadIdx.x;
    const int w = tid >> 6, l = tid & 63, lo = l & 15, hi = l >> 4;
    const int row0 = blockIdx.x * 64;

    for (int i = tid; i < 64 * 128; i += 256) {
        int r = i >> 7, c = i & 127;
        int obj = row0 + r;
        float v = 0.f;
        if (obj < NOBJ) {
            if (c < 64) v = lse_from_sum(ssum64[(size_t)obj * 64 + c]);
            else v = emb[(size_t)obj * 64 + (c - 64)];
        }
        uin[i ^ ((r & 7) << 3)] = f2b(v);
    }
    __syncthreads();

    const int arow = w * 16 + lo;
    const int asw = (arow & 7) << 3;
    f32x4 acc[8];
#pragma unroll
    for (int n = 0; n < 8; ++n) { float b = bi[n * 16 + lo]; acc[n] = (f32x4){b, b, b, b}; }
#pragma unroll
    for (int kk = 0; kk < 4; ++kk) {
        bf16x8 a = *(const bf16x8*)&uin[(arow * 128 + kk * 32 + hi * 8) ^ asw];
#pragma unroll
        for (int n = 0; n < 8; ++n) {
            bf16x8 b = *(const bf16x8*)&g_wbf[OFF_PWI + (n * 16 + lo) * 128 + kk * 32 + hi * 8];
            acc[n] = __builtin_amdgcn_mfma_f32_16x16x32_bf16(a, b, acc[n], 0, 0, 0);
        }
    }
#pragma unroll
    for (int n = 0; n < 8; ++n) {
#pragma unroll
        for (int r = 0; r < 4; ++r) {
            int row = w * 16 + hi * 4 + r;
            int col = n * 16 + lo;
            h[(row * 128 + col) ^ ((row & 7) << 3)] = f2b(mish_fast(acc[n][r]));
        }
    }
    __syncthreads();
    f32x4 acc2[4];
#pragma unroll
    for (int n = 0; n < 4; ++n) { float b = bo[n * 16 + lo]; acc2[n] = (f32x4){b, b, b, b}; }
#pragma unroll
    for (int kk = 0; kk < 4; ++kk) {
        bf16x8 a = *(const bf16x8*)&h[(arow * 128 + kk * 32 + hi * 8) ^ asw];
#pragma unroll
        for (int n = 0; n < 4; ++n) {
            bf16x8 b = *(const bf16x8*)&g_wbf[OFF_PWO + (n * 16 + lo) * 128 + kk * 32 + hi * 8];
            acc2[n] = __builtin_amdgcn_mfma_f32_16x16x32_bf16(a, b, acc2[n], 0, 0, 0);
        }
    }
#pragma unroll
    for (int n = 0; n < 4; ++n) {
        int col = n * 16 + lo;
#pragma unroll
        for (int r = 0; r < 4; ++r) {
            int row = w * 16 + hi * 4 + r;
            int obj = row0 + row;
            if (obj < NOBJ)
                out[(size_t)obj * 64 + col] = emb[(size_t)obj * 64 + col] + acc2[n][r];
        }
    }
}

static inline size_t align256(size_t x) { return (x + 255) & ~(size_t)255; }

extern "C" void kernel_launch(void* const* d_in, const int* in_sizes, int n_in,
                              void* d_out, int out_size, void* d_ws, size_t ws_size,
                              hipStream_t stream) {
    const float* emb = (const float*)d_in[0];
    const int* iu = (const int*)d_in[1];
    const int* ib = (const int*)d_in[2];
    const int* it = (const int*)d_in[3];
    const float* uwi = (const float*)d_in[4];
    const float* ubi = (const float*)d_in[5];
    const float* uwo = (const float*)d_in[6];
    const float* ubo = (const float*)d_in[7];
    const float* bwi = (const float*)d_in[8];
    const float* bbi = (const float*)d_in[9];
    const float* bwo = (const float*)d_in[10];
    const float* bbo = (const float*)d_in[11];
    const float* twi = (const float*)d_in[12];
    const float* tbi = (const float*)d_in[13];
    const float* two_ = (const float*)d_in[14];
    const float* tbo = (const float*)d_in[15];
    const float* pwi = (const float*)d_in[16];
    const float* pbi = (const float*)d_in[17];
    const float* pwo = (const float*)d_in[18];
    const float* pbo = (const float*)d_in[19];

    const int nU = in_sizes[1];
    const int nB = in_sizes[2];
    const int nT = in_sizes[3];
    const int rowsU = nU;
    const int rowsB = nB / 2;
    const int rowsT = nT / 3;
    const long long NREF = (long long)nU + nB + nT;

    const size_t seg = (size_t)NOBJ * 64;
    const int gU = (rowsU + 127) / 128;
    const int gB = (rowsB + 127) / 128;
    const int gT = (rowsT + 127) / 128;
    const int nblkScan = (NOBJ + 255) / 256;
    const int gPrep = (NOBJ * 16 + 255) / 256;

    // ---- CSR workspace layout ----
    char* p = (char*)d_ws;
    u16* msgs = (u16*)p;        p += align256(2 * (size_t)NREF * 64);
    u32* counts = (u32*)p;      p += align256(4 * (size_t)NOBJ);
    u32* offs = (u32*)p;        p += align256(4 * (size_t)NOBJ);
    u32* cursor = (u32*)p;      p += align256(4 * (size_t)NOBJ);
    u32* bsum = (u32*)p;        p += align256(4 * 512);
    u32* slotByRef = (u32*)p;   p += align256(4 * (size_t)NREF);
    u16* emb_bf = (u16*)p;      p += align256(2 * seg);
    const size_t need = (size_t)(p - (char*)d_ws);

    if (ws_size >= need) {
        // ========== CSR path: sorted f16 msg writes, streaming aggregate, 0 fp atomics ==========
        prep_kernel<<<gPrep, 256, 0, stream>>>(uwi, uwo, bwi, bwo, twi, two_, pwi, pwo,
                                               emb, emb_bf, counts, cursor);
        int gRef = (int)((NREF + 255) / 256);
        hist_kernel<<<gRef, 256, 0, stream>>>(iu, nU, ib, nB, it, nT, counts);
        scan1_kernel<<<nblkScan, 256, 0, stream>>>(counts, offs, bsum);
        scan2_kernel<<<1, 512, 0, stream>>>(bsum, nblkScan);
        slot_kernel<<<gRef, 256, 0, stream>>>(iu, nU, ib, nB, it, nT, offs, bsum, cursor, slotByRef);

        rel_pass_mfma<64, 8, 3, OFF_UWI, OFF_UWO><<<gU, 512, 0, stream>>>(
            emb_bf, iu, rowsU, ubi, ubo, nullptr, msgs, slotByRef, 0LL);
        rel_pass_mfma<128, 8, 3, OFF_BWI, OFF_BWO><<<gB, 512, 0, stream>>>(
            emb_bf, ib, rowsB, bbi, bbo, nullptr, msgs, slotByRef, (long long)nU);
        rel_pass_mfma<192, 8, 3, OFF_TWI, OFF_TWO><<<gT, 512, 0, stream>>>(
            emb_bf, it, rowsT, tbi, tbo, nullptr, msgs, slotByRef, (long long)(nU + nB));

        // LSE buffer lives in d_out (update reads each row before writing it)
        float* lsebuf = (float*)d_out;
        agg_kernel<<<(NOBJ + 3) / 4, 256, 0, stream>>>(msgs, offs, bsum, counts, lsebuf);
        update_from_lse<<<(NOBJ + 63) / 64, 256, 0, stream>>>(
            emb, lsebuf, pbi, pbo, (float*)d_out);
    } else {
        // ========== f64 single-pass fallback ==========
        double* ssum64 = (double*)d_ws;
        u16* emb_bf2 = (u16*)((char*)d_ws + seg * sizeof(double));
        prep_kernel<<<gPrep, 256, 0, stream>>>(uwi, uwo, bwi, bwo, twi, two_, pwi, pwo,
                                               emb, emb_bf2, nullptr, nullptr);
        hipMemsetAsync(ssum64, 0, seg * sizeof(double), stream);
        rel_pass_mfma<64, 8, 2, OFF_UWI, OFF_UWO><<<gU, 512, 0, stream>>>(
            emb_bf2, iu, rowsU, ubi, ubo, ssum64, nullptr, nullptr, 0);
        rel_pass_mfma<128, 8, 2, OFF_BWI, OFF_BWO><<<gB, 512, 0, stream>>>(
            emb_bf2, ib, rowsB, bbi, bbo, ssum64, nullptr, nullptr, 0);
        rel_pass_mfma<192, 8, 2, OFF_TWI, OFF_TWO><<<gT, 512, 0, stream>>>(
            emb_bf2, it, rowsT, tbi, tbo, ssum64, nullptr, nullptr, 0);
        update_mfma_f64<<<(NOBJ + 63) / 64, 256, 0, stream>>>(
            emb, ssum64, pbi, pbo, (float*)d_out);
    }
}

// Round 12
// 351.764 us; speedup vs baseline: 1.1074x; 1.0277x over previous
//
#include <hip/hip_runtime.h>
#include <math.h>

#define NOBJ 100000
#define SMOOTH 12.0f

typedef __attribute__((ext_vector_type(8))) short bf16x8;
typedef __attribute__((ext_vector_type(4))) short bf16x4;
typedef __attribute__((ext_vector_type(4))) float f32x4;
typedef unsigned short u16;
typedef unsigned int u32;
typedef unsigned long long u64;

// bf16 weight table
#define OFF_UWI 0
#define OFF_UWO 4096
#define OFF_BWI 8192
#define OFF_BWO 24576
#define OFF_TWI 40960
#define OFF_TWO 77824
#define OFF_PWI 114688
#define OFF_PWO 131072
#define WTOT    139264
__device__ u16 g_wbf[WTOT];

__device__ __forceinline__ u16 f2b(float x) {
    union { float f; u32 u; } v; v.f = x;
    u32 r = v.u + 0x7FFFu + ((v.u >> 16) & 1);  // RNE
    return (u16)(r >> 16);
}
__device__ __forceinline__ float b2f(u16 b) {
    union { u32 u; float f; } v; v.u = ((u32)b) << 16; return v.f;
}
__device__ __forceinline__ float mish_fast(float x) {
    float e = __expf(fminf(x, 15.f));
    float t = __builtin_fmaf(e, e, 2.f * e);
    return x * t * __builtin_amdgcn_rcpf(t + 2.f);
}
__device__ __forceinline__ double exp12_f64(float m) {
    float t = m * (SMOOTH * 1.4426950408889634f);
    float n = floorf(t);
    float f = exp2f(t - n);
    return ldexp((double)f, (int)n);
}
__device__ __forceinline__ float lse_from_sum(double S) {
    if (S == 0.0) return -3.0701134573253942f;  // log(1e-16)/12
    union { double d; u64 u; } vu; vu.d = S;
    int k = (int)((vu.u >> 52) & 0x7FF) - 1022;
    vu.u = (vu.u & 0x000FFFFFFFFFFFFFULL) | 0x3FE0000000000000ULL;
    float fr = (float)vu.d;
    return ((float)k + __log2f(fr)) * 0.057762265046662105f;  // *ln2/12
}

// weights -> bf16 table, emb -> bf16 table, zero counts/cursor
__global__ void prep_kernel(const float* __restrict__ uwi, const float* __restrict__ uwo,
                            const float* __restrict__ bwi, const float* __restrict__ bwo,
                            const float* __restrict__ twi, const float* __restrict__ two_,
                            const float* __restrict__ pwi, const float* __restrict__ pwo,
                            const float* __restrict__ emb, u16* __restrict__ emb_bf,
                            u32* __restrict__ counts, u32* __restrict__ cursor) {
    int i = blockIdx.x * 256 + threadIdx.x;
    if (i < WTOT) {
        const float* src; int off;
        if      (i < OFF_UWO) { src = uwi; off = OFF_UWI; }
        else if (i < OFF_BWI) { src = uwo; off = OFF_UWO; }
        else if (i < OFF_BWO) { src = bwi; off = OFF_BWI; }
        else if (i < OFF_TWI) { src = bwo; off = OFF_BWO; }
        else if (i < OFF_TWO) { src = twi; off = OFF_TWI; }
        else if (i < OFF_PWI) { src = two_; off = OFF_TWO; }
        else if (i < OFF_PWO) { src = pwi; off = OFF_PWI; }
        else                  { src = pwo; off = OFF_PWO; }
        g_wbf[i] = f2b(src[i - off]);
    }
    if (i < NOBJ * 16) {
        float4 v = ((const float4*)emb)[i];
        ushort4 o;
        o.x = f2b(v.x); o.y = f2b(v.y); o.z = f2b(v.z); o.w = f2b(v.w);
        ((ushort4*)emb_bf)[i] = o;
    }
    if (counts && i < NOBJ) { counts[i] = 0u; cursor[i] = 0u; }
}

__device__ __forceinline__ int lookup_obj(long long m,
                                          const int* __restrict__ iu, int nU,
                                          const int* __restrict__ ib, int nB,
                                          const int* __restrict__ it) {
    if (m < nU) return iu[m];
    m -= nU;
    if (m < nB) return ib[m];
    return it[m - nB];
}

// ---------- CSR build ----------
__global__ void hist_kernel(const int* __restrict__ iu, int nU,
                            const int* __restrict__ ib, int nB,
                            const int* __restrict__ it, int nT,
                            u32* __restrict__ counts) {
    long long t = (long long)blockIdx.x * 256 + threadIdx.x;
    if (t >= (long long)nU + nB + nT) return;
    atomicAdd(&counts[lookup_obj(t, iu, nU, ib, nB, it)], 1u);
}

__global__ void scan1_kernel(const u32* __restrict__ counts, u32* __restrict__ offs,
                             u32* __restrict__ bsum) {
    __shared__ u32 s[256];
    int t = threadIdx.x;
    int g = blockIdx.x * 256 + t;
    u32 v = (g < NOBJ) ? counts[g] : 0u;
    s[t] = v; __syncthreads();
    for (int off = 1; off < 256; off <<= 1) {
        u32 x = (t >= off) ? s[t - off] : 0u; __syncthreads();
        s[t] += x; __syncthreads();
    }
    if (g < NOBJ) offs[g] = s[t] - v;
    if (t == 255) bsum[blockIdx.x] = s[255];
}

__global__ void scan2_kernel(u32* __restrict__ bsum, int nblk) {
    __shared__ u32 s[512];
    int t = threadIdx.x;
    u32 v = (t < nblk) ? bsum[t] : 0u;
    s[t] = v; __syncthreads();
    for (int off = 1; off < 512; off <<= 1) {
        u32 x = (t >= off) ? s[t - off] : 0u; __syncthreads();
        s[t] += x; __syncthreads();
    }
    if (t < nblk) bsum[t] = s[t] - v;
}

__global__ void slot_kernel(const int* __restrict__ iu, int nU,
                            const int* __restrict__ ib, int nB,
                            const int* __restrict__ it, int nT,
                            const u32* __restrict__ offs, const u32* __restrict__ bsum,
                            u32* __restrict__ cursor, u32* __restrict__ slotByRef) {
    long long t = (long long)blockIdx.x * 256 + threadIdx.x;
    if (t >= (long long)nU + nB + nT) return;
    int obj = lookup_obj(t, iu, nU, ib, nB, it);
    u32 pos = atomicAdd(&cursor[obj], 1u);
    slotByRef[t] = offs[obj] + bsum[obj >> 8] + pos;
}

// per-thread weight-stage load (global -> regs) and write (regs -> LDS), 8B granule
#define LOADW(s_, reg_) do {                                                   \
    const int woff_ = ((s_) < KT) ? WOFF_I : WOFF_O;                           \
    const int cs_ = ((s_) < KT) ? (s_) : (s_) - KT;                            \
    _Pragma("unroll")                                                          \
    for (int q = 0; q < NCH; ++q) {                                            \
        int o_ = (tid + q * NTHR) * 4;                                         \
        int j_ = o_ >> 5, c_ = o_ & 31;                                        \
        reg_[q] = *(const bf16x4*)&g_wbf[woff_ + j_ * D + cs_ * 32 + c_];      \
    } } while (0)

#define WRITEW(buf_, reg_) do {                                                \
    _Pragma("unroll")                                                          \
    for (int q = 0; q < NCH; ++q) {                                            \
        int o_ = (tid + q * NTHR) * 4;                                         \
        int j_ = o_ >> 5, c_ = o_ & 31;                                        \
        *(bf16x4*)&wlds[buf_][(j_ * 32 + c_) ^ ((j_ & 3) << 3)] = reg_[q];     \
    } } while (0)

// ---------- fused relation MLP: 32-col weight stages, 2-deep register prefetch ----------
// xs: x -> h -> msg in place (strip-local per wave). One barrier per stage.
// MODE 2: f64 atomicAdd exp(12*m) | MODE 3: CSR slot-directed f16 msg write
template<int D, int MW, int MODE, int WOFF_I, int WOFF_O>
__global__ __launch_bounds__(64 * MW)
void rel_pass_mfma(const u16* __restrict__ emb_bf,
                   const int* __restrict__ idx, int nRows,
                   const float* __restrict__ bi, const float* __restrict__ bo,
                   double* __restrict__ ssum64,
                   u16* __restrict__ msgs_out, const u32* __restrict__ slotByRef,
                   long long baseRef) {
    constexpr int ARITY = D / 64;
    constexpr int NT = D / 16;
    constexpr int KT = D / 32;        // stages per layer (32 cols each)
    constexpr int ST = 2 * KT;        // total stages (both layers)
    constexpr int M = MW * 16;
    constexpr int NTHR = 64 * MW;
    constexpr int NCH = D * 32 / 4 / NTHR;   // 8B chunks per thread per stage
    __shared__ u16 xs[M * D];
    __shared__ u16 wlds[2][D * 32];
    __shared__ int objsm[M * ARITY];
    __shared__ u32 slotm[M * ARITY];

    const int tid = threadIdx.x;
    const int w = tid >> 6, l = tid & 63;
    const int lo = l & 15, hi = l >> 4;
    const int row0 = blockIdx.x * M;

    bf16x4 wrA[NCH], wrB[NCH];

    for (int i = tid; i < M * ARITY; i += NTHR) {
        int row = row0 + i / ARITY;
        bool ok = (row < nRows);
        objsm[i] = ok ? idx[(size_t)row * ARITY + i % ARITY] : -1;
        if (MODE == 3)
            slotm[i] = ok ? slotByRef[baseRef + (long long)row0 * ARITY + i] : 0xFFFFFFFFu;
    }
    LOADW(0, wrA);                 // stage-0 weights in flight during objsm barrier + gather
    LOADW(1, wrB);
    __syncthreads();               // objsm ready

    // bf16 gather: 16B per lane-iteration, XOR-swizzled LDS
    for (int i = tid; i < M * D / 8; i += NTHR) {
        int r = i / (D / 8), c8 = i % (D / 8);
        int obj = objsm[r * ARITY + (c8 >> 3)];
        bf16x8 v = {0, 0, 0, 0, 0, 0, 0, 0};
        if (obj >= 0) v = *(const bf16x8*)(emb_bf + (size_t)obj * 64 + (c8 & 7) * 8);
        *(bf16x8*)&xs[(r * D + c8 * 8) ^ ((r & 7) << 3)] = v;
    }
    WRITEW(0, wrA);
    __syncthreads();               // xs + wlds[0] ready

    f32x4 acc[NT];
    const int arow = w * 16 + lo;
    const int asw = (arow & 7) << 3;
#pragma unroll
    for (int n = 0; n < NT; ++n) { float b = bi[n * 16 + lo]; acc[n] = (f32x4){b, b, b, b}; }

#pragma unroll
    for (int s = 0; s < ST; ++s) {
        // register prefetch two stages ahead; LDS write-ahead one stage
        if (s + 2 < ST) {
            if (s & 1) { LOADW(s + 2, wrB); } else { LOADW(s + 2, wrA); }
        }
        if (s + 1 < ST) {
            if (s & 1) { WRITEW((s + 1) & 1, wrA); } else { WRITEW((s + 1) & 1, wrB); }
        }
        // MFMA for stage s (K=32)
        {
            const int kk = (s < KT) ? s : s - KT;
            bf16x8 a = *(const bf16x8*)&xs[(arow * D + kk * 32 + hi * 8) ^ asw];
#pragma unroll
            for (int n = 0; n < NT; ++n) {
                int j = n * 16 + lo;
                bf16x8 b = *(const bf16x8*)&wlds[s & 1][(j * 32 + hi * 8) ^ ((j & 3) << 3)];
                acc[n] = __builtin_amdgcn_mfma_f32_16x16x32_bf16(a, b, acc[n], 0, 0, 0);
            }
        }
        if (s == KT - 1) {
            // layer transition: mish -> own strip; acc = bo + x (residual folded)
#pragma unroll
            for (int n = 0; n < NT; ++n) {
                float bov = bo[n * 16 + lo];
#pragma unroll
                for (int r = 0; r < 4; ++r) {
                    int row = w * 16 + hi * 4 + r;
                    int col = n * 16 + lo;
                    int sidx = (row * D + col) ^ ((row & 7) << 3);
                    float xv = b2f(xs[sidx]);
                    xs[sidx] = f2b(mish_fast(acc[n][r]));
                    acc[n][r] = bov + xv;
                }
            }
        }
        __syncthreads();
    }

    if (MODE == 3) {
#pragma unroll
        for (int n = 0; n < NT; ++n) {
            int col = n * 16 + lo;
#pragma unroll
            for (int r = 0; r < 4; ++r) {
                int row = w * 16 + hi * 4 + r;
                _Float16 hv = (_Float16)acc[n][r];
                xs[(row * D + col) ^ ((row & 7) << 3)] = *(u16*)&hv;
            }
        }
        __syncthreads();
        for (int i = tid; i < M * D / 8; i += NTHR) {
            int u = i * 8;
            int row = u / D, off = u - row * D;
            u32 slot = slotm[row * ARITY + (off >> 6)];
            if (slot == 0xFFFFFFFFu) continue;
            *(bf16x8*)(msgs_out + (size_t)slot * 64 + (off & 63)) =
                *(const bf16x8*)&xs[u ^ ((row & 7) << 3)];
        }
    } else {
#pragma unroll
        for (int n = 0; n < NT; ++n) {
            int col = n * 16 + lo;
#pragma unroll
            for (int r = 0; r < 4; ++r) {
                int row = w * 16 + hi * 4 + r;
                int obj = objsm[row * ARITY + (col >> 6)];
                if (obj < 0) continue;
                unsafeAtomicAdd(&ssum64[(size_t)obj * 64 + (col & 63)], exp12_f64(acc[n][r]));
            }
        }
    }
}

// ---------- aggregate: one wave per object, lane = column, zero LDS/shuffles ----------
__global__ __launch_bounds__(256)
void agg_kernel(const u16* __restrict__ msgs,
                const u32* __restrict__ offs, const u32* __restrict__ bsum,
                const u32* __restrict__ counts,
                float* __restrict__ lse_out) {
    int o = blockIdx.x * 4 + (threadIdx.x >> 6);
    int l = threadIdx.x & 63;
    if (o >= NOBJ) return;
    u32 off = offs[o] + bsum[o >> 8];
    u32 n = counts[o];
    const u16* mrow = msgs + (size_t)off * 64 + l;
    double S0 = 0.0, S1 = 0.0, S2 = 0.0, S3 = 0.0;
    u32 j = 0;
    for (; j + 4 <= n; j += 4) {
        u16 h0 = mrow[(size_t)(j + 0) * 64];
        u16 h1 = mrow[(size_t)(j + 1) * 64];
        u16 h2 = mrow[(size_t)(j + 2) * 64];
        u16 h3 = mrow[(size_t)(j + 3) * 64];
        S0 += exp12_f64((float)(*(const _Float16*)&h0));
        S1 += exp12_f64((float)(*(const _Float16*)&h1));
        S2 += exp12_f64((float)(*(const _Float16*)&h2));
        S3 += exp12_f64((float)(*(const _Float16*)&h3));
    }
    for (; j < n; ++j) {
        u16 h = mrow[(size_t)j * 64];
        S0 += exp12_f64((float)(*(const _Float16*)&h));
    }
    lse_out[(size_t)o * 64 + l] = lse_from_sum((S0 + S1) + (S2 + S3));
}

// ---------- update MLP reading f32 LSE (lsein may alias out; reads precede writes per block) ----------
__global__ __launch_bounds__(256)
void update_from_lse(const float* __restrict__ emb, const float* lsein,
                     const float* __restrict__ bi, const float* __restrict__ bo,
                     float* out) {
    __shared__ u16 uin[64 * 128];
    __shared__ u16 h[64 * 128];
    const int tid = threadIdx.x;
    const int w = tid >> 6, l = tid & 63, lo = l & 15, hi = l >> 4;
    const int row0 = blockIdx.x * 64;

    for (int i = tid; i < 64 * 128; i += 256) {
        int r = i >> 7, c = i & 127;
        int obj = row0 + r;
        float v = 0.f;
        if (obj < NOBJ) {
            if (c < 64) v = lsein[(size_t)obj * 64 + c];
            else v = emb[(size_t)obj * 64 + (c - 64)];
        }
        uin[i ^ ((r & 7) << 3)] = f2b(v);
    }
    __syncthreads();

    const int arow = w * 16 + lo;
    const int asw = (arow & 7) << 3;
    f32x4 acc[8];
#pragma unroll
    for (int n = 0; n < 8; ++n) { float b = bi[n * 16 + lo]; acc[n] = (f32x4){b, b, b, b}; }
#pragma unroll
    for (int kk = 0; kk < 4; ++kk) {
        bf16x8 a = *(const bf16x8*)&uin[(arow * 128 + kk * 32 + hi * 8) ^ asw];
#pragma unroll
        for (int n = 0; n < 8; ++n) {
            bf16x8 b = *(const bf16x8*)&g_wbf[OFF_PWI + (n * 16 + lo) * 128 + kk * 32 + hi * 8];
            acc[n] = __builtin_amdgcn_mfma_f32_16x16x32_bf16(a, b, acc[n], 0, 0, 0);
        }
    }
#pragma unroll
    for (int n = 0; n < 8; ++n) {
#pragma unroll
        for (int r = 0; r < 4; ++r) {
            int row = w * 16 + hi * 4 + r;
            int col = n * 16 + lo;
            h[(row * 128 + col) ^ ((row & 7) << 3)] = f2b(mish_fast(acc[n][r]));
        }
    }
    __syncthreads();
    f32x4 acc2[4];
#pragma unroll
    for (int n = 0; n < 4; ++n) { float b = bo[n * 16 + lo]; acc2[n] = (f32x4){b, b, b, b}; }
#pragma unroll
    for (int kk = 0; kk < 4; ++kk) {
        bf16x8 a = *(const bf16x8*)&h[(arow * 128 + kk * 32 + hi * 8) ^ asw];
#pragma unroll
        for (int n = 0; n < 4; ++n) {
            bf16x8 b = *(const bf16x8*)&g_wbf[OFF_PWO + (n * 16 + lo) * 128 + kk * 32 + hi * 8];
            acc2[n] = __builtin_amdgcn_mfma_f32_16x16x32_bf16(a, b, acc2[n], 0, 0, 0);
        }
    }
#pragma unroll
    for (int n = 0; n < 4; ++n) {
        int col = n * 16 + lo;
#pragma unroll
        for (int r = 0; r < 4; ++r) {
            int row = w * 16 + hi * 4 + r;
            int obj = row0 + row;
            if (obj < NOBJ)
                out[(size_t)obj * 64 + col] = emb[(size_t)obj * 64 + col] + acc2[n][r];
        }
    }
}

// fallback update (reads f64 sums)
__global__ __launch_bounds__(256)
void update_mfma_f64(const float* __restrict__ emb, const double* __restrict__ ssum64,
                     const float* __restrict__ bi, const float* __restrict__ bo,
                     float* __restrict__ out) {
    __shared__ u16 uin[64 * 128];
    __shared__ u16 h[64 * 128];
    const int tid = threadIdx.x;
    const int w = tid >> 6, l = tid & 63, lo = l & 15, hi = l >> 4;
    const int row0 = blockIdx.x * 64;

    for (int i = tid; i < 64 * 128; i += 256) {
        int r = i >> 7, c = i & 127;
        int obj = row0 + r;
        float v = 0.f;
        if (obj < NOBJ) {
            if (c < 64) v = lse_from_sum(ssum64[(size_t)obj * 64 + c]);
            else v = emb[(size_t)obj * 64 + (c - 64)];
        }
        uin[i ^ ((r & 7) << 3)] = f2b(v);
    }
    __syncthreads();

    const int arow = w * 16 + lo;
    const int asw = (arow & 7) << 3;
    f32x4 acc[8];
#pragma unroll
    for (int n = 0; n < 8; ++n) { float b = bi[n * 16 + lo]; acc[n] = (f32x4){b, b, b, b}; }
#pragma unroll
    for (int kk = 0; kk < 4; ++kk) {
        bf16x8 a = *(const bf16x8*)&uin[(arow * 128 + kk * 32 + hi * 8) ^ asw];
#pragma unroll
        for (int n = 0; n < 8; ++n) {
            bf16x8 b = *(const bf16x8*)&g_wbf[OFF_PWI + (n * 16 + lo) * 128 + kk * 32 + hi * 8];
            acc[n] = __builtin_amdgcn_mfma_f32_16x16x32_bf16(a, b, acc[n], 0, 0, 0);
        }
    }
#pragma unroll
    for (int n = 0; n < 8; ++n) {
#pragma unroll
        for (int r = 0; r < 4; ++r) {
            int row = w * 16 + hi * 4 + r;
            int col = n * 16 + lo;
            h[(row * 128 + col) ^ ((row & 7) << 3)] = f2b(mish_fast(acc[n][r]));
        }
    }
    __syncthreads();
    f32x4 acc2[4];
#pragma unroll
    for (int n = 0; n < 4; ++n) { float b = bo[n * 16 + lo]; acc2[n] = (f32x4){b, b, b, b}; }
#pragma unroll
    for (int kk = 0; kk < 4; ++kk) {
        bf16x8 a = *(const bf16x8*)&h[(arow * 128 + kk * 32 + hi * 8) ^ asw];
#pragma unroll
        for (int n = 0; n < 4; ++n) {
            bf16x8 b = *(const bf16x8*)&g_wbf[OFF_PWO + (n * 16 + lo) * 128 + kk * 32 + hi * 8];
            acc2[n] = __builtin_amdgcn_mfma_f32_16x16x32_bf16(a, b, acc2[n], 0, 0, 0);
        }
    }
#pragma unroll
    for (int n = 0; n < 4; ++n) {
        int col = n * 16 + lo;
#pragma unroll
        for (int r = 0; r < 4; ++r) {
            int row = w * 16 + hi * 4 + r;
            int obj = row0 + row;
            if (obj < NOBJ)
                out[(size_t)obj * 64 + col] = emb[(size_t)obj * 64 + col] + acc2[n][r];
        }
    }
}

static inline size_t align256(size_t x) { return (x + 255) & ~(size_t)255; }

extern "C" void kernel_launch(void* const* d_in, const int* in_sizes, int n_in,
                              void* d_out, int out_size, void* d_ws, size_t ws_size,
                              hipStream_t stream) {
    const float* emb = (const float*)d_in[0];
    const int* iu = (const int*)d_in[1];
    const int* ib = (const int*)d_in[2];
    const int* it = (const int*)d_in[3];
    const float* uwi = (const float*)d_in[4];
    const float* ubi = (const float*)d_in[5];
    const float* uwo = (const float*)d_in[6];
    const float* ubo = (const float*)d_in[7];
    const float* bwi = (const float*)d_in[8];
    const float* bbi = (const float*)d_in[9];
    const float* bwo = (const float*)d_in[10];
    const float* bbo = (const float*)d_in[11];
    const float* twi = (const float*)d_in[12];
    const float* tbi = (const float*)d_in[13];
    const float* two_ = (const float*)d_in[14];
    const float* tbo = (const float*)d_in[15];
    const float* pwi = (const float*)d_in[16];
    const float* pbi = (const float*)d_in[17];
    const float* pwo = (const float*)d_in[18];
    const float* pbo = (const float*)d_in[19];

    const int nU = in_sizes[1];
    const int nB = in_sizes[2];
    const int nT = in_sizes[3];
    const int rowsU = nU;
    const int rowsB = nB / 2;
    const int rowsT = nT / 3;
    const long long NREF = (long long)nU + nB + nT;

    const size_t seg = (size_t)NOBJ * 64;
    const int gU = (rowsU + 127) / 128;
    const int gB = (rowsB + 127) / 128;
    const int gT = (rowsT + 127) / 128;
    const int nblkScan = (NOBJ + 255) / 256;
    const int gPrep = (NOBJ * 16 + 255) / 256;

    // ---- CSR workspace layout ----
    char* p = (char*)d_ws;
    u16* msgs = (u16*)p;        p += align256(2 * (size_t)NREF * 64);
    u32* counts = (u32*)p;      p += align256(4 * (size_t)NOBJ);
    u32* offs = (u32*)p;        p += align256(4 * (size_t)NOBJ);
    u32* cursor = (u32*)p;      p += align256(4 * (size_t)NOBJ);
    u32* bsum = (u32*)p;        p += align256(4 * 512);
    u32* slotByRef = (u32*)p;   p += align256(4 * (size_t)NREF);
    u16* emb_bf = (u16*)p;      p += align256(2 * seg);
    const size_t need = (size_t)(p - (char*)d_ws);

    if (ws_size >= need) {
        // ========== CSR path: sorted f16 msg writes, streaming aggregate, 0 fp atomics ==========
        prep_kernel<<<gPrep, 256, 0, stream>>>(uwi, uwo, bwi, bwo, twi, two_, pwi, pwo,
                                               emb, emb_bf, counts, cursor);
        int gRef = (int)((NREF + 255) / 256);
        hist_kernel<<<gRef, 256, 0, stream>>>(iu, nU, ib, nB, it, nT, counts);
        scan1_kernel<<<nblkScan, 256, 0, stream>>>(counts, offs, bsum);
        scan2_kernel<<<1, 512, 0, stream>>>(bsum, nblkScan);
        slot_kernel<<<gRef, 256, 0, stream>>>(iu, nU, ib, nB, it, nT, offs, bsum, cursor, slotByRef);

        rel_pass_mfma<64, 8, 3, OFF_UWI, OFF_UWO><<<gU, 512, 0, stream>>>(
            emb_bf, iu, rowsU, ubi, ubo, nullptr, msgs, slotByRef, 0LL);
        rel_pass_mfma<128, 8, 3, OFF_BWI, OFF_BWO><<<gB, 512, 0, stream>>>(
            emb_bf, ib, rowsB, bbi, bbo, nullptr, msgs, slotByRef, (long long)nU);
        rel_pass_mfma<192, 8, 3, OFF_TWI, OFF_TWO><<<gT, 512, 0, stream>>>(
            emb_bf, it, rowsT, tbi, tbo, nullptr, msgs, slotByRef, (long long)(nU + nB));

        // LSE buffer lives in d_out (update reads each row before writing it)
        float* lsebuf = (float*)d_out;
        agg_kernel<<<(NOBJ + 3) / 4, 256, 0, stream>>>(msgs, offs, bsum, counts, lsebuf);
        update_from_lse<<<(NOBJ + 63) / 64, 256, 0, stream>>>(
            emb, lsebuf, pbi, pbo, (float*)d_out);
    } else {
        // ========== f64 single-pass fallback ==========
        double* ssum64 = (double*)d_ws;
        u16* emb_bf2 = (u16*)((char*)d_ws + seg * sizeof(double));
        prep_kernel<<<gPrep, 256, 0, stream>>>(uwi, uwo, bwi, bwo, twi, two_, pwi, pwo,
                                               emb, emb_bf2, nullptr, nullptr);
        hipMemsetAsync(ssum64, 0, seg * sizeof(double), stream);
        rel_pass_mfma<64, 8, 2, OFF_UWI, OFF_UWO><<<gU, 512, 0, stream>>>(
            emb_bf2, iu, rowsU, ubi, ubo, ssum64, nullptr, nullptr, 0);
        rel_pass_mfma<128, 8, 2, OFF_BWI, OFF_BWO><<<gB, 512, 0, stream>>>(
            emb_bf2, ib, rowsB, bbi, bbo, ssum64, nullptr, nullptr, 0);
        rel_pass_mfma<192, 8, 2, OFF_TWI, OFF_TWO><<<gT, 512, 0, stream>>>(
            emb_bf2, it, rowsT, tbi, tbo, ssum64, nullptr, nullptr, 0);
        update_mfma_f64<<<(NOBJ + 63) / 64, 256, 0, stream>>>(
            emb, ssum64, pbi, pbo, (float*)d_out);
    }
}